// Round 1
// baseline (5982.194 us; speedup 1.0000x reference)
//
#include <hip/hip_runtime.h>
#include <hip/hip_bf16.h>

#define NN 100000
#define F 128
#define C_OUT 14

// ---------------------------------------------------------------------------
// Scatter-add: one 32-thread group per edge; each thread moves a float4 of
// the source row into agg[dst] via 4 atomicAdds. Lane 0 of each group bumps
// the degree counter (layer-1 only).
// ---------------------------------------------------------------------------
__global__ __launch_bounds__(256) void scatter_kernel(
    const float* __restrict__ xin,
    const int* __restrict__ src, const int* __restrict__ dst,
    float* __restrict__ agg, float* __restrict__ deg,
    int nEdges, int addDeg)
{
    long long tid = (long long)blockIdx.x * 256 + threadIdx.x;
    int e = (int)(tid >> 5);
    if (e >= nEdges) return;
    int f4 = ((int)tid & 31) * 4;
    int s = src[e];
    int d = dst[e];
    const float4 v = *(const float4*)(xin + (long long)s * F + f4);
    float* ap = agg + (long long)d * F + f4;
    atomicAdd(ap + 0, v.x);
    atomicAdd(ap + 1, v.y);
    atomicAdd(ap + 2, v.z);
    atomicAdd(ap + 3, v.w);
    if (addDeg && (((int)tid & 31) == 0)) atomicAdd(deg + d, 1.0f);
}

// ---------------------------------------------------------------------------
// Layer 1: h = relu(agg/deg @ Wl + x @ Wr + b), 128x128 weights.
// Block = 256 threads handles 8 nodes: thread (sub=tid/32, lane=tid%32)
// computes columns j4..j4+3 for node sub. a/x rows staged in LDS (scaled by
// 1/deg); W read from global (128 KB, identical stream on every wave ->
// L1/L2 broadcast).
// ---------------------------------------------------------------------------
__global__ __launch_bounds__(256) void gemm1_kernel(
    const float* __restrict__ x, const float* __restrict__ agg,
    const float* __restrict__ deg,
    const float* __restrict__ Wl, const float* __restrict__ Wr,
    const float* __restrict__ b, float* __restrict__ h)
{
    __shared__ float ax_s[8][2][F];   // 8 KB

    const int lane = threadIdx.x & 31;
    const int sub  = threadIdx.x >> 5;
    const int j4   = lane * 4;
    const int n    = blockIdx.x * 8 + sub;

    if (n < NN) {
        float inv = 1.0f / fmaxf(deg[n], 1.0f);
        float4 av = *(const float4*)(agg + (long long)n * F + j4);
        float4 xv = *(const float4*)(x   + (long long)n * F + j4);
        av.x *= inv; av.y *= inv; av.z *= inv; av.w *= inv;
        *(float4*)&ax_s[sub][0][j4] = av;
        *(float4*)&ax_s[sub][1][j4] = xv;
    }
    __syncthreads();

    const float4 bv = *(const float4*)(b + j4);
    float a0 = bv.x, a1 = bv.y, a2 = bv.z, a3 = bv.w;

    #pragma unroll 8
    for (int k = 0; k < F; ++k) {
        float av = ax_s[sub][0][k];
        float xv = ax_s[sub][1][k];
        float4 wl = ((const float4*)Wl)[k * 32 + lane];
        float4 wr = ((const float4*)Wr)[k * 32 + lane];
        a0 += av * wl.x + xv * wr.x;
        a1 += av * wl.y + xv * wr.y;
        a2 += av * wl.z + xv * wr.z;
        a3 += av * wl.w + xv * wr.w;
    }

    if (n < NN) {
        float4 o;
        o.x = fmaxf(a0, 0.0f);
        o.y = fmaxf(a1, 0.0f);
        o.z = fmaxf(a2, 0.0f);
        o.w = fmaxf(a3, 0.0f);
        *(float4*)(h + (long long)n * F + j4) = o;
    }
}

// ---------------------------------------------------------------------------
// Layer 2 + dual log_softmax, fused. Block = 256 threads; thread tid<252 maps
// to (nslot = tid/14, c = tid%14), 18 nodes per block. W2 tables are 7 KB
// each -> L1-resident. 14 outputs per node staged in LDS for the softmax.
// Output: d_out[0 .. N*sf) = x_SF row-major, then x_Ptx.
// ---------------------------------------------------------------------------
__global__ __launch_bounds__(256) void gemm2_kernel(
    const float* __restrict__ h, const float* __restrict__ agg,
    const float* __restrict__ deg,
    const float* __restrict__ Wl, const float* __restrict__ Wr,
    const float* __restrict__ b,
    const int* __restrict__ sf_ptr, float* __restrict__ out)
{
    __shared__ float sm[18][C_OUT];
    const int tid   = threadIdx.x;
    const int nslot = tid / C_OUT;
    const int c     = tid % C_OUT;
    const int n     = blockIdx.x * 18 + nslot;
    const int sf    = *sf_ptr;
    const bool active = (tid < 18 * C_OUT) && (n < NN);

    float acc = 0.0f;
    if (active) {
        acc = b[c];
        const float inv = 1.0f / fmaxf(deg[n], 1.0f);
        const float* ar = agg + (long long)n * F;
        const float* hr = h   + (long long)n * F;
        #pragma unroll 4
        for (int k = 0; k < F; ++k) {
            acc += ar[k] * inv * Wl[k * C_OUT + c] + hr[k] * Wr[k * C_OUT + c];
        }
        sm[nslot][c] = acc;
    }
    __syncthreads();

    if (active) {
        const int lo = (c < sf) ? 0  : sf;
        const int hi = (c < sf) ? sf : C_OUT;
        float m = -1e30f;
        for (int i = lo; i < hi; ++i) m = fmaxf(m, sm[nslot][i]);
        float s = 0.0f;
        for (int i = lo; i < hi; ++i) s += expf(sm[nslot][i] - m);
        const float v = acc - m - logf(s);
        if (c < sf) out[(long long)n * sf + c] = v;
        else        out[(long long)NN * sf + (long long)n * (C_OUT - sf) + (c - sf)] = v;
    }
}

// ---------------------------------------------------------------------------
extern "C" void kernel_launch(void* const* d_in, const int* in_sizes, int n_in,
                              void* d_out, int out_size, void* d_ws, size_t ws_size,
                              hipStream_t stream)
{
    const float* x     = (const float*)d_in[0];
    const int*   ei    = (const int*)d_in[1];
    const int*   sfp   = (const int*)d_in[2];
    const float* W1l   = (const float*)d_in[3];
    const float* W1r   = (const float*)d_in[4];
    const float* b1    = (const float*)d_in[5];
    const float* W2l   = (const float*)d_in[6];
    const float* W2r   = (const float*)d_in[7];
    const float* b2    = (const float*)d_in[8];
    float*       out   = (float*)d_out;

    const int E = in_sizes[1] / 2;
    const int* src = ei;
    const int* dst = ei + E;

    float* deg = (float*)d_ws;                   // NN floats
    float* agg = deg + NN;                       // NN*F floats
    float* h   = agg + (size_t)NN * F;           // NN*F floats

    // zero deg + agg (contiguous)
    hipMemsetAsync(deg, 0, (size_t)(NN + (size_t)NN * F) * sizeof(float), stream);

    const long long sthreads = (long long)E * 32;
    const int sblocks = (int)((sthreads + 255) / 256);

    // layer 1
    scatter_kernel<<<sblocks, 256, 0, stream>>>(x, src, dst, agg, deg, E, 1);
    gemm1_kernel<<<(NN + 7) / 8, 256, 0, stream>>>(x, agg, deg, W1l, W1r, b1, h);

    // layer 2
    hipMemsetAsync(agg, 0, (size_t)NN * F * sizeof(float), stream);
    scatter_kernel<<<sblocks, 256, 0, stream>>>(h, src, dst, agg, nullptr, E, 0);
    gemm2_kernel<<<(NN + 17) / 18, 256, 0, stream>>>(h, agg, deg, W2l, W2r, b2, sfp, out);
}

// Round 2
// 906.958 us; speedup vs baseline: 6.5959x; 6.5959x over previous
//
#include <hip/hip_runtime.h>
#include <hip/hip_bf16.h>

#define NN 100000
#define F 128
#define C_OUT 14
#define SCAN_CHUNK 1024
#define NBLK ((NN + SCAN_CHUNK - 1) / SCAN_CHUNK)   // 98 blocks

// ---------------------------------------------------------------------------
// CSR build step 1: histogram of in-degrees.
// ---------------------------------------------------------------------------
__global__ __launch_bounds__(256) void hist_kernel(
    const int* __restrict__ dst, int* __restrict__ cnt, int E)
{
    int e = blockIdx.x * 256 + threadIdx.x;
    if (e < E) atomicAdd(&cnt[dst[e]], 1);
}

// ---------------------------------------------------------------------------
// CSR build step 2a: per-1024-chunk exclusive scan (256 thr x 4 items).
// Writes chunk-local exclusive prefix to rowptr, chunk total to blocksum.
// ---------------------------------------------------------------------------
__global__ __launch_bounds__(256) void scan_local_kernel(
    const int* __restrict__ cnt, int* __restrict__ rowptr,
    int* __restrict__ blocksum)
{
    __shared__ int sm[256];
    const int tid  = threadIdx.x;
    const int base = blockIdx.x * SCAN_CHUNK + tid * 4;
    int v0 = (base + 0 < NN) ? cnt[base + 0] : 0;
    int v1 = (base + 1 < NN) ? cnt[base + 1] : 0;
    int v2 = (base + 2 < NN) ? cnt[base + 2] : 0;
    int v3 = (base + 3 < NN) ? cnt[base + 3] : 0;
    const int t = v0 + v1 + v2 + v3;
    sm[tid] = t;
    __syncthreads();
    int acc = t;
    for (int off = 1; off < 256; off <<= 1) {
        int other = (tid >= off) ? sm[tid - off] : 0;
        __syncthreads();
        acc += other;
        sm[tid] = acc;
        __syncthreads();
    }
    const int excl = acc - t;
    if (base + 0 < NN) rowptr[base + 0] = excl;
    if (base + 1 < NN) rowptr[base + 1] = excl + v0;
    if (base + 2 < NN) rowptr[base + 2] = excl + v0 + v1;
    if (base + 3 < NN) rowptr[base + 3] = excl + v0 + v1 + v2;
    if (tid == 255) blocksum[blockIdx.x] = acc;
}

// ---------------------------------------------------------------------------
// CSR build step 2b: scan the 98 chunk totals (single block).
// ---------------------------------------------------------------------------
__global__ __launch_bounds__(128) void scan_block_kernel(int* __restrict__ blocksum)
{
    __shared__ int sm[128];
    const int tid = threadIdx.x;
    const int v = (tid < NBLK) ? blocksum[tid] : 0;
    sm[tid] = v;
    __syncthreads();
    int acc = v;
    for (int off = 1; off < 128; off <<= 1) {
        int other = (tid >= off) ? sm[tid - off] : 0;
        __syncthreads();
        acc += other;
        sm[tid] = acc;
        __syncthreads();
    }
    if (tid < NBLK) blocksum[tid] = acc - v;   // exclusive
}

// ---------------------------------------------------------------------------
// CSR build step 2c: add chunk offsets; init cursor copy and 1/max(deg,1).
// ---------------------------------------------------------------------------
__global__ __launch_bounds__(256) void finalize_kernel(
    const int* __restrict__ cnt, int* __restrict__ rowptr,
    int* __restrict__ cursor, float* __restrict__ invdeg,
    const int* __restrict__ blocksum)
{
    int i = blockIdx.x * 256 + threadIdx.x;
    if (i >= NN) return;
    int r = rowptr[i] + blocksum[i / SCAN_CHUNK];
    rowptr[i] = r;
    cursor[i] = r;
    invdeg[i] = 1.0f / (float)max(cnt[i], 1);
}

// ---------------------------------------------------------------------------
// CSR build step 3: scatter src ids into eidx (atomic cursor bump; int
// atomics on 0.4 MB of counters — cheap, order within a row is irrelevant).
// ---------------------------------------------------------------------------
__global__ __launch_bounds__(256) void fill_kernel(
    const int* __restrict__ src, const int* __restrict__ dst,
    int* __restrict__ cursor, int* __restrict__ eidx, int E)
{
    int e = blockIdx.x * 256 + threadIdx.x;
    if (e < E) {
        int p = atomicAdd(&cursor[dst[e]], 1);
        eidx[p] = src[e];
    }
}

// ---------------------------------------------------------------------------
// Layer 1 fused: gather-mean of neighbor rows + h = relu(agg@Wl + x@Wr + b).
// 256 threads = 8 groups of 32 lanes; group <-> node. Phase A: each lane
// accumulates a float4 column slice over the node's neighbors (512 B
// coalesced per edge), scales by 1/deg, stages into LDS next to the node's
// own x row. Phase B: dense 128x128 GEMM, lane computes 4 output columns.
// ---------------------------------------------------------------------------
__global__ __launch_bounds__(256) void layer1_kernel(
    const float* __restrict__ x, const int* __restrict__ eidx,
    const int* __restrict__ rowptr, const int* __restrict__ cnt,
    const float* __restrict__ invdeg,
    const float* __restrict__ Wl, const float* __restrict__ Wr,
    const float* __restrict__ b, float* __restrict__ h)
{
    __shared__ float ax_s[8][2][F];   // 8 KB

    const int lane = threadIdx.x & 31;
    const int sub  = threadIdx.x >> 5;
    const int j4   = lane * 4;
    const int n    = blockIdx.x * 8 + sub;

    if (n < NN) {
        const int start = rowptr[n];
        const int len   = cnt[n];
        float4 acc = make_float4(0.f, 0.f, 0.f, 0.f);
        for (int i = 0; i < len; ++i) {
            const int s = eidx[start + i];
            const float4 v = *(const float4*)(x + (long long)s * F + j4);
            acc.x += v.x; acc.y += v.y; acc.z += v.z; acc.w += v.w;
        }
        const float inv = invdeg[n];
        acc.x *= inv; acc.y *= inv; acc.z *= inv; acc.w *= inv;
        *(float4*)&ax_s[sub][0][j4] = acc;
        *(float4*)&ax_s[sub][1][j4] = *(const float4*)(x + (long long)n * F + j4);
    }
    __syncthreads();

    const float4 bv = *(const float4*)(b + j4);
    float a0 = bv.x, a1 = bv.y, a2 = bv.z, a3 = bv.w;

    #pragma unroll 8
    for (int k = 0; k < F; ++k) {
        const float av = ax_s[sub][0][k];
        const float xv = ax_s[sub][1][k];
        const float4 wl = ((const float4*)Wl)[k * 32 + lane];
        const float4 wr = ((const float4*)Wr)[k * 32 + lane];
        a0 += av * wl.x + xv * wr.x;
        a1 += av * wl.y + xv * wr.y;
        a2 += av * wl.z + xv * wr.z;
        a3 += av * wl.w + xv * wr.w;
    }

    if (n < NN) {
        float4 o;
        o.x = fmaxf(a0, 0.0f);
        o.y = fmaxf(a1, 0.0f);
        o.z = fmaxf(a2, 0.0f);
        o.w = fmaxf(a3, 0.0f);
        *(float4*)(h + (long long)n * F + j4) = o;
    }
}

// ---------------------------------------------------------------------------
// Layer 2 fused: gather-mean over h + 128->14 GEMM + dual log_softmax.
// Phase A mirrors layer1 (gather from h). Phase B: lanes 0..13 of each group
// each compute one output class (scalar dot over the two LDS rows; W2 is
// 7 KB x2, L1-resident, broadcast LDS reads). Phase C: segment log_softmax.
// ---------------------------------------------------------------------------
__global__ __launch_bounds__(256) void layer2_kernel(
    const float* __restrict__ h, const int* __restrict__ eidx,
    const int* __restrict__ rowptr, const int* __restrict__ cnt,
    const float* __restrict__ invdeg,
    const float* __restrict__ Wl, const float* __restrict__ Wr,
    const float* __restrict__ b,
    const int* __restrict__ sf_ptr, float* __restrict__ out)
{
    __shared__ float rows[8][2][F];   // 8 KB
    __shared__ float sm[8][C_OUT];

    const int lane = threadIdx.x & 31;
    const int sub  = threadIdx.x >> 5;
    const int j4   = lane * 4;
    const int n    = blockIdx.x * 8 + sub;

    if (n < NN) {
        const int start = rowptr[n];
        const int len   = cnt[n];
        float4 acc = make_float4(0.f, 0.f, 0.f, 0.f);
        for (int i = 0; i < len; ++i) {
            const int s = eidx[start + i];
            const float4 v = *(const float4*)(h + (long long)s * F + j4);
            acc.x += v.x; acc.y += v.y; acc.z += v.z; acc.w += v.w;
        }
        const float inv = invdeg[n];
        acc.x *= inv; acc.y *= inv; acc.z *= inv; acc.w *= inv;
        *(float4*)&rows[sub][0][j4] = acc;
        *(float4*)&rows[sub][1][j4] = *(const float4*)(h + (long long)n * F + j4);
    }
    __syncthreads();

    float acc = 0.0f;
    const int c = lane;
    const bool active = (n < NN) && (lane < C_OUT);
    if (active) {
        acc = b[c];
        #pragma unroll 4
        for (int k = 0; k < F; ++k) {
            acc += rows[sub][0][k] * Wl[k * C_OUT + c]
                 + rows[sub][1][k] * Wr[k * C_OUT + c];
        }
        sm[sub][c] = acc;
    }
    __syncthreads();

    if (active) {
        const int sf = *sf_ptr;
        const int lo = (c < sf) ? 0  : sf;
        const int hi = (c < sf) ? sf : C_OUT;
        float m = -1e30f;
        for (int i = lo; i < hi; ++i) m = fmaxf(m, sm[sub][i]);
        float s = 0.0f;
        for (int i = lo; i < hi; ++i) s += expf(sm[sub][i] - m);
        const float v = acc - m - logf(s);
        if (c < sf) out[(long long)n * sf + c] = v;
        else        out[(long long)NN * sf + (long long)n * (C_OUT - sf) + (c - sf)] = v;
    }
}

// ---------------------------------------------------------------------------
extern "C" void kernel_launch(void* const* d_in, const int* in_sizes, int n_in,
                              void* d_out, int out_size, void* d_ws, size_t ws_size,
                              hipStream_t stream)
{
    const float* x   = (const float*)d_in[0];
    const int*   ei  = (const int*)d_in[1];
    const int*   sfp = (const int*)d_in[2];
    const float* W1l = (const float*)d_in[3];
    const float* W1r = (const float*)d_in[4];
    const float* b1  = (const float*)d_in[5];
    const float* W2l = (const float*)d_in[6];
    const float* W2r = (const float*)d_in[7];
    const float* b2  = (const float*)d_in[8];
    float*       out = (float*)d_out;

    const int E  = in_sizes[1] / 2;
    const int E4 = (E + 3) & ~3;           // keep later offsets 16B-aligned
    const int* src = ei;
    const int* dst = ei + E;

    // ws layout (4-byte words)
    int*   cnt      = (int*)d_ws;                      // NN
    int*   rowptr   = cnt + NN;                        // NN
    int*   cursor   = rowptr + NN;                     // NN
    float* invdeg   = (float*)(cursor + NN);           // NN
    int*   blocksum = (int*)(invdeg + NN);             // 128
    int*   eidx     = blocksum + 128;                  // E4
    float* h        = (float*)(eidx + E4);             // NN*F

    // zero the degree histogram only
    hipMemsetAsync(cnt, 0, (size_t)NN * sizeof(int), stream);

    const int eblocks = (E + 255) / 256;
    const int nblocks = (NN + 255) / 256;

    // CSR build (shared by both layers)
    hist_kernel      <<<eblocks, 256, 0, stream>>>(dst, cnt, E);
    scan_local_kernel<<<NBLK,    256, 0, stream>>>(cnt, rowptr, blocksum);
    scan_block_kernel<<<1,       128, 0, stream>>>(blocksum);
    finalize_kernel  <<<nblocks, 256, 0, stream>>>(cnt, rowptr, cursor, invdeg, blocksum);
    fill_kernel      <<<eblocks, 256, 0, stream>>>(src, dst, cursor, eidx, E);

    // fused gather + GEMM layers
    layer1_kernel<<<(NN + 7) / 8, 256, 0, stream>>>(x, eidx, rowptr, cnt, invdeg,
                                                    W1l, W1r, b1, h);
    layer2_kernel<<<(NN + 7) / 8, 256, 0, stream>>>(h, eidx, rowptr, cnt, invdeg,
                                                    W2l, W2r, b2, sfp, out);
}

// Round 3
// 763.689 us; speedup vs baseline: 7.8333x; 1.1876x over previous
//
#include <hip/hip_runtime.h>
#include <hip/hip_bf16.h>

#define NN 100000
#define F 128
#define C_OUT 14
#define ZP 16                                  // padded width of z/r rows
#define SCAN_CHUNK 1024
#define NBLK ((NN + SCAN_CHUNK - 1) / SCAN_CHUNK)   // 98 blocks

// ---------------------------------------------------------------------------
// CSR build step 1: histogram of in-degrees.
// ---------------------------------------------------------------------------
__global__ __launch_bounds__(256) void hist_kernel(
    const int* __restrict__ dst, int* __restrict__ cnt, int E)
{
    int e = blockIdx.x * 256 + threadIdx.x;
    if (e < E) atomicAdd(&cnt[dst[e]], 1);
}

// ---------------------------------------------------------------------------
// CSR build step 2a: per-1024-chunk exclusive scan (256 thr x 4 items).
// ---------------------------------------------------------------------------
__global__ __launch_bounds__(256) void scan_local_kernel(
    const int* __restrict__ cnt, int* __restrict__ rowptr,
    int* __restrict__ blocksum)
{
    __shared__ int sm[256];
    const int tid  = threadIdx.x;
    const int base = blockIdx.x * SCAN_CHUNK + tid * 4;
    int v0 = (base + 0 < NN) ? cnt[base + 0] : 0;
    int v1 = (base + 1 < NN) ? cnt[base + 1] : 0;
    int v2 = (base + 2 < NN) ? cnt[base + 2] : 0;
    int v3 = (base + 3 < NN) ? cnt[base + 3] : 0;
    const int t = v0 + v1 + v2 + v3;
    sm[tid] = t;
    __syncthreads();
    int acc = t;
    for (int off = 1; off < 256; off <<= 1) {
        int other = (tid >= off) ? sm[tid - off] : 0;
        __syncthreads();
        acc += other;
        sm[tid] = acc;
        __syncthreads();
    }
    const int excl = acc - t;
    if (base + 0 < NN) rowptr[base + 0] = excl;
    if (base + 1 < NN) rowptr[base + 1] = excl + v0;
    if (base + 2 < NN) rowptr[base + 2] = excl + v0 + v1;
    if (base + 3 < NN) rowptr[base + 3] = excl + v0 + v1 + v2;
    if (tid == 255) blocksum[blockIdx.x] = acc;
}

// ---------------------------------------------------------------------------
// CSR build step 2b: scan the 98 chunk totals (single block).
// ---------------------------------------------------------------------------
__global__ __launch_bounds__(128) void scan_block_kernel(int* __restrict__ blocksum)
{
    __shared__ int sm[128];
    const int tid = threadIdx.x;
    const int v = (tid < NBLK) ? blocksum[tid] : 0;
    sm[tid] = v;
    __syncthreads();
    int acc = v;
    for (int off = 1; off < 128; off <<= 1) {
        int other = (tid >= off) ? sm[tid - off] : 0;
        __syncthreads();
        acc += other;
        sm[tid] = acc;
        __syncthreads();
    }
    if (tid < NBLK) blocksum[tid] = acc - v;   // exclusive
}

// ---------------------------------------------------------------------------
// CSR build step 2c: add chunk offsets; init cursor copy and 1/max(deg,1).
// ---------------------------------------------------------------------------
__global__ __launch_bounds__(256) void finalize_kernel(
    const int* __restrict__ cnt, int* __restrict__ rowptr,
    int* __restrict__ cursor, float* __restrict__ invdeg,
    const int* __restrict__ blocksum)
{
    int i = blockIdx.x * 256 + threadIdx.x;
    if (i >= NN) return;
    int r = rowptr[i] + blocksum[i / SCAN_CHUNK];
    rowptr[i] = r;
    cursor[i] = r;
    invdeg[i] = 1.0f / (float)max(cnt[i], 1);
}

// ---------------------------------------------------------------------------
// CSR build step 3: scatter src ids into eidx.
// ---------------------------------------------------------------------------
__global__ __launch_bounds__(256) void fill_kernel(
    const int* __restrict__ src, const int* __restrict__ dst,
    int* __restrict__ cursor, int* __restrict__ eidx, int E)
{
    int e = blockIdx.x * 256 + threadIdx.x;
    if (e < E) {
        int p = atomicAdd(&cursor[dst[e]], 1);
        eidx[p] = src[e];
    }
}

// ---------------------------------------------------------------------------
// Layer 1 fused: gather-mean of neighbor rows + h = relu(agg@Wl + x@Wr + b).
// Gather loop unrolled x4 with independent accumulators: 4 row loads in
// flight per wave (was 1 -> latency-bound at VALUBusy=20%).
// ---------------------------------------------------------------------------
__global__ __launch_bounds__(256) void layer1_kernel(
    const float* __restrict__ x, const int* __restrict__ eidx,
    const int* __restrict__ rowptr, const int* __restrict__ cnt,
    const float* __restrict__ invdeg,
    const float* __restrict__ Wl, const float* __restrict__ Wr,
    const float* __restrict__ b, float* __restrict__ h)
{
    __shared__ float ax_s[8][2][F];   // 8 KB

    const int lane = threadIdx.x & 31;
    const int sub  = threadIdx.x >> 5;
    const int j4   = lane * 4;
    const int n    = blockIdx.x * 8 + sub;

    if (n < NN) {
        const int start = rowptr[n];
        const int len   = cnt[n];
        float4 a0 = make_float4(0.f,0.f,0.f,0.f);
        float4 a1 = a0, a2 = a0, a3 = a0;
        int i = 0;
        for (; i + 4 <= len; i += 4) {
            const int s0 = eidx[start + i + 0];
            const int s1 = eidx[start + i + 1];
            const int s2 = eidx[start + i + 2];
            const int s3 = eidx[start + i + 3];
            const float4 v0 = *(const float4*)(x + (long long)s0 * F + j4);
            const float4 v1 = *(const float4*)(x + (long long)s1 * F + j4);
            const float4 v2 = *(const float4*)(x + (long long)s2 * F + j4);
            const float4 v3 = *(const float4*)(x + (long long)s3 * F + j4);
            a0.x += v0.x; a0.y += v0.y; a0.z += v0.z; a0.w += v0.w;
            a1.x += v1.x; a1.y += v1.y; a1.z += v1.z; a1.w += v1.w;
            a2.x += v2.x; a2.y += v2.y; a2.z += v2.z; a2.w += v2.w;
            a3.x += v3.x; a3.y += v3.y; a3.z += v3.z; a3.w += v3.w;
        }
        for (; i < len; ++i) {
            const int s = eidx[start + i];
            const float4 v = *(const float4*)(x + (long long)s * F + j4);
            a0.x += v.x; a0.y += v.y; a0.z += v.z; a0.w += v.w;
        }
        const float inv = invdeg[n];
        float4 acc;
        acc.x = (a0.x + a1.x + a2.x + a3.x) * inv;
        acc.y = (a0.y + a1.y + a2.y + a3.y) * inv;
        acc.z = (a0.z + a1.z + a2.z + a3.z) * inv;
        acc.w = (a0.w + a1.w + a2.w + a3.w) * inv;
        *(float4*)&ax_s[sub][0][j4] = acc;
        *(float4*)&ax_s[sub][1][j4] = *(const float4*)(x + (long long)n * F + j4);
    }
    __syncthreads();

    const float4 bv = *(const float4*)(b + j4);
    float c0 = bv.x, c1 = bv.y, c2 = bv.z, c3 = bv.w;

    #pragma unroll 8
    for (int k = 0; k < F; ++k) {
        const float av = ax_s[sub][0][k];
        const float xv = ax_s[sub][1][k];
        const float4 wl = ((const float4*)Wl)[k * 32 + lane];
        const float4 wr = ((const float4*)Wr)[k * 32 + lane];
        c0 += av * wl.x + xv * wr.x;
        c1 += av * wl.y + xv * wr.y;
        c2 += av * wl.z + xv * wr.z;
        c3 += av * wl.w + xv * wr.w;
    }

    if (n < NN) {
        float4 o;
        o.x = fmaxf(c0, 0.0f);
        o.y = fmaxf(c1, 0.0f);
        o.z = fmaxf(c2, 0.0f);
        o.w = fmaxf(c3, 0.0f);
        *(float4*)(h + (long long)n * F + j4) = o;
    }
}

// ---------------------------------------------------------------------------
// Layer 2a: z = h @ W2_l, r = h @ W2_r + b2 (dense, sequential h read).
// Mean-agg commutes with the linear map, so we shrink rows BEFORE gathering:
// gather volume drops 512 B/edge -> 64 B/edge.
// Block = 8 groups of 32 lanes; group stages one h row in LDS; lanes 0..13
// compute z cols, lanes 16..29 compute r cols.
// ---------------------------------------------------------------------------
__global__ __launch_bounds__(256) void gemm2_pre_kernel(
    const float* __restrict__ h,
    const float* __restrict__ Wl, const float* __restrict__ Wr,
    const float* __restrict__ b,
    float* __restrict__ z, float* __restrict__ r)
{
    __shared__ float h_s[8][F];   // 4 KB
    const int lane = threadIdx.x & 31;
    const int sub  = threadIdx.x >> 5;
    const int n    = blockIdx.x * 8 + sub;

    if (n < NN)
        *(float4*)&h_s[sub][lane * 4] = *(const float4*)(h + (long long)n * F + lane * 4);
    __syncthreads();

    const int c = lane & 15;
    if (n < NN && c < C_OUT) {
        const bool isZ = lane < 16;
        const float* W = isZ ? Wl : Wr;
        float acc = isZ ? 0.0f : b[c];
        #pragma unroll 8
        for (int k = 0; k < F; ++k)
            acc += h_s[sub][k] * W[k * C_OUT + c];
        (isZ ? z : r)[(long long)n * ZP + c] = acc;
    }
}

// ---------------------------------------------------------------------------
// Layer 2b: out = log_softmax_segments( mean-agg(z) + r ).
// 4 lanes per node (float4 of the 16-wide padded row), 64 nodes per block.
// Gather unrolled x4. Softmax: one thread per node over the LDS row.
// ---------------------------------------------------------------------------
__global__ __launch_bounds__(256) void agg2_kernel(
    const float* __restrict__ z, const float* __restrict__ r,
    const int* __restrict__ eidx, const int* __restrict__ rowptr,
    const int* __restrict__ cnt, const float* __restrict__ invdeg,
    const int* __restrict__ sf_ptr, float* __restrict__ out)
{
    __shared__ float sm[64][ZP + 1];   // pad -> stride 17 words, conflict-free

    const int lane4 = threadIdx.x & 3;
    const int slot  = threadIdx.x >> 2;
    const int n     = blockIdx.x * 64 + slot;
    const int j4    = lane4 * 4;

    if (n < NN) {
        const int start = rowptr[n];
        const int len   = cnt[n];
        float4 a0 = make_float4(0.f,0.f,0.f,0.f);
        float4 a1 = a0, a2 = a0, a3 = a0;
        int i = 0;
        for (; i + 4 <= len; i += 4) {
            const int s0 = eidx[start + i + 0];
            const int s1 = eidx[start + i + 1];
            const int s2 = eidx[start + i + 2];
            const int s3 = eidx[start + i + 3];
            const float4 v0 = *(const float4*)(z + (long long)s0 * ZP + j4);
            const float4 v1 = *(const float4*)(z + (long long)s1 * ZP + j4);
            const float4 v2 = *(const float4*)(z + (long long)s2 * ZP + j4);
            const float4 v3 = *(const float4*)(z + (long long)s3 * ZP + j4);
            a0.x += v0.x; a0.y += v0.y; a0.z += v0.z; a0.w += v0.w;
            a1.x += v1.x; a1.y += v1.y; a1.z += v1.z; a1.w += v1.w;
            a2.x += v2.x; a2.y += v2.y; a2.z += v2.z; a2.w += v2.w;
            a3.x += v3.x; a3.y += v3.y; a3.z += v3.z; a3.w += v3.w;
        }
        for (; i < len; ++i) {
            const int s = eidx[start + i];
            const float4 v = *(const float4*)(z + (long long)s * ZP + j4);
            a0.x += v.x; a0.y += v.y; a0.z += v.z; a0.w += v.w;
        }
        const float inv = invdeg[n];
        const float4 rv = *(const float4*)(r + (long long)n * ZP + j4);
        float4 res;
        res.x = (a0.x + a1.x + a2.x + a3.x) * inv + rv.x;
        res.y = (a0.y + a1.y + a2.y + a3.y) * inv + rv.y;
        res.z = (a0.z + a1.z + a2.z + a3.z) * inv + rv.z;
        res.w = (a0.w + a1.w + a2.w + a3.w) * inv + rv.w;
        *(float4*)&sm[slot][j4] = res;
    }
    __syncthreads();

    if (threadIdx.x < 64) {
        const int n2 = blockIdx.x * 64 + threadIdx.x;
        if (n2 < NN) {
            const int sf = *sf_ptr;
            const float* row = sm[threadIdx.x];
            // segment [0, sf)
            float m = -1e30f;
            for (int c = 0; c < sf; ++c) m = fmaxf(m, row[c]);
            float s = 0.0f;
            for (int c = 0; c < sf; ++c) s += expf(row[c] - m);
            float ls = m + logf(s);
            for (int c = 0; c < sf; ++c)
                out[(long long)n2 * sf + c] = row[c] - ls;
            // segment [sf, 14)
            m = -1e30f;
            for (int c = sf; c < C_OUT; ++c) m = fmaxf(m, row[c]);
            s = 0.0f;
            for (int c = sf; c < C_OUT; ++c) s += expf(row[c] - m);
            ls = m + logf(s);
            const int pt = C_OUT - sf;
            for (int c = sf; c < C_OUT; ++c)
                out[(long long)NN * sf + (long long)n2 * pt + (c - sf)] = row[c] - ls;
        }
    }
}

// ---------------------------------------------------------------------------
extern "C" void kernel_launch(void* const* d_in, const int* in_sizes, int n_in,
                              void* d_out, int out_size, void* d_ws, size_t ws_size,
                              hipStream_t stream)
{
    const float* x   = (const float*)d_in[0];
    const int*   ei  = (const int*)d_in[1];
    const int*   sfp = (const int*)d_in[2];
    const float* W1l = (const float*)d_in[3];
    const float* W1r = (const float*)d_in[4];
    const float* b1  = (const float*)d_in[5];
    const float* W2l = (const float*)d_in[6];
    const float* W2r = (const float*)d_in[7];
    const float* b2  = (const float*)d_in[8];
    float*       out = (float*)d_out;

    const int E  = in_sizes[1] / 2;
    const int E4 = (E + 3) & ~3;
    const int* src = ei;
    const int* dst = ei + E;

    // ws layout (4-byte words; every segment 16B-aligned)
    int*   cnt      = (int*)d_ws;                      // NN
    int*   rowptr   = cnt + NN;                        // NN
    int*   cursor   = rowptr + NN;                     // NN
    float* invdeg   = (float*)(cursor + NN);           // NN
    int*   blocksum = (int*)(invdeg + NN);             // 128
    int*   eidx     = blocksum + 128;                  // E4
    float* h        = (float*)(eidx + E4);             // NN*F
    float* z        = h + (size_t)NN * F;              // NN*ZP
    float* r        = z + (size_t)NN * ZP;             // NN*ZP

    hipMemsetAsync(cnt, 0, (size_t)NN * sizeof(int), stream);

    const int eblocks = (E + 255) / 256;
    const int nblocks = (NN + 255) / 256;

    // CSR build (shared by both layers)
    hist_kernel      <<<eblocks, 256, 0, stream>>>(dst, cnt, E);
    scan_local_kernel<<<NBLK,    256, 0, stream>>>(cnt, rowptr, blocksum);
    scan_block_kernel<<<1,       128, 0, stream>>>(blocksum);
    finalize_kernel  <<<nblocks, 256, 0, stream>>>(cnt, rowptr, cursor, invdeg, blocksum);
    fill_kernel      <<<eblocks, 256, 0, stream>>>(src, dst, cursor, eidx, E);

    // layer 1 (fused gather + GEMM)
    layer1_kernel<<<(NN + 7) / 8, 256, 0, stream>>>(x, eidx, rowptr, cnt, invdeg,
                                                    W1l, W1r, b1, h);
    // layer 2 (GEMM first, then 64 B/edge gather + softmax)
    gemm2_pre_kernel<<<(NN + 7) / 8, 256, 0, stream>>>(h, W2l, W2r, b2, z, r);
    agg2_kernel<<<(NN + 63) / 64, 256, 0, stream>>>(z, r, eidx, rowptr, cnt, invdeg,
                                                    sfp, out);
}

// Round 4
// 508.005 us; speedup vs baseline: 11.7758x; 1.5033x over previous
//
#include <hip/hip_runtime.h>
#include <hip/hip_bf16.h>

#define NN 100000
#define F 128
#define C_OUT 14
#define ZP 16
#define SCAN_CHUNK 1024
#define NBLK ((NN + SCAN_CHUNK - 1) / SCAN_CHUNK)   // 98 blocks

// ---------------- bf16 helpers (manual, zero API risk) ----------------------
static __device__ __forceinline__ unsigned short f2bf(float f) {
    unsigned int u = __float_as_uint(f);
    unsigned int r = (u + 0x7fffu + ((u >> 16) & 1u)) >> 16;   // RTN-even
    return (unsigned short)r;
}
static __device__ __forceinline__ unsigned int pack2(float a, float b) {
    return (unsigned int)f2bf(a) | ((unsigned int)f2bf(b) << 16);
}
static __device__ __forceinline__ void unpack2(unsigned int u, float& lo, float& hi) {
    lo = __uint_as_float(u << 16);
    hi = __uint_as_float(u & 0xffff0000u);
}

// ---------------------------------------------------------------------------
// x (fp32) -> xb (bf16), flat.
// ---------------------------------------------------------------------------
__global__ __launch_bounds__(256) void cvt_kernel(
    const float* __restrict__ x, unsigned short* __restrict__ xb)
{
    int i = blockIdx.x * 256 + threadIdx.x;          // one float4 per thread
    if (i >= NN * F / 4) return;
    const float4 v = ((const float4*)x)[i];
    uint2 o;
    o.x = pack2(v.x, v.y);
    o.y = pack2(v.z, v.w);
    ((uint2*)xb)[i] = o;
}

// ---------------------------- CSR build ------------------------------------
__global__ __launch_bounds__(256) void hist_kernel(
    const int* __restrict__ dst, int* __restrict__ cnt, int E)
{
    int e = blockIdx.x * 256 + threadIdx.x;
    if (e < E) atomicAdd(&cnt[dst[e]], 1);
}

__global__ __launch_bounds__(256) void scan_local_kernel(
    const int* __restrict__ cnt, int* __restrict__ rowptr,
    int* __restrict__ blocksum)
{
    __shared__ int sm[256];
    const int tid  = threadIdx.x;
    const int base = blockIdx.x * SCAN_CHUNK + tid * 4;
    int v0 = (base + 0 < NN) ? cnt[base + 0] : 0;
    int v1 = (base + 1 < NN) ? cnt[base + 1] : 0;
    int v2 = (base + 2 < NN) ? cnt[base + 2] : 0;
    int v3 = (base + 3 < NN) ? cnt[base + 3] : 0;
    const int t = v0 + v1 + v2 + v3;
    sm[tid] = t;
    __syncthreads();
    int acc = t;
    for (int off = 1; off < 256; off <<= 1) {
        int other = (tid >= off) ? sm[tid - off] : 0;
        __syncthreads();
        acc += other;
        sm[tid] = acc;
        __syncthreads();
    }
    const int excl = acc - t;
    if (base + 0 < NN) rowptr[base + 0] = excl;
    if (base + 1 < NN) rowptr[base + 1] = excl + v0;
    if (base + 2 < NN) rowptr[base + 2] = excl + v0 + v1;
    if (base + 3 < NN) rowptr[base + 3] = excl + v0 + v1 + v2;
    if (tid == 255) blocksum[blockIdx.x] = acc;
}

__global__ __launch_bounds__(128) void scan_block_kernel(int* __restrict__ blocksum)
{
    __shared__ int sm[128];
    const int tid = threadIdx.x;
    const int v = (tid < NBLK) ? blocksum[tid] : 0;
    sm[tid] = v;
    __syncthreads();
    int acc = v;
    for (int off = 1; off < 128; off <<= 1) {
        int other = (tid >= off) ? sm[tid - off] : 0;
        __syncthreads();
        acc += other;
        sm[tid] = acc;
        __syncthreads();
    }
    if (tid < NBLK) blocksum[tid] = acc - v;
}

__global__ __launch_bounds__(256) void finalize_kernel(
    const int* __restrict__ cnt, int* __restrict__ rowptr,
    int* __restrict__ cursor, float* __restrict__ invdeg,
    const int* __restrict__ blocksum)
{
    int i = blockIdx.x * 256 + threadIdx.x;
    if (i >= NN) return;
    int r = rowptr[i] + blocksum[i / SCAN_CHUNK];
    rowptr[i] = r;
    cursor[i] = r;
    invdeg[i] = 1.0f / (float)max(cnt[i], 1);
}

__global__ __launch_bounds__(256) void fill_kernel(
    const int* __restrict__ src, const int* __restrict__ dst,
    int* __restrict__ cursor, int* __restrict__ eidx, int E)
{
    int e = blockIdx.x * 256 + threadIdx.x;
    if (e < E) {
        int p = atomicAdd(&cursor[dst[e]], 1);
        eidx[p] = src[e];
    }
}

// ---------------------------------------------------------------------------
// pre1: pq = [ x@W1l | x@W1r + b1 ]  (bf16 out, [NN][256]).
// blockIdx.y = chunk (0 -> W1l cols 0..127, 1 -> W1r + b1 cols 128..255).
// M_TILE=128, per-thread 8x8 register tile; A (bf16, transposed to [k][m])
// and W (bf16, [k][c]) staged in LDS = exactly 64 KB; 2 blocks/CU.
// ---------------------------------------------------------------------------
__global__ __launch_bounds__(256, 2) void pre1_kernel(
    const unsigned short* __restrict__ xb,
    const float* __restrict__ W1l, const float* __restrict__ W1r,
    const float* __restrict__ b1, unsigned short* __restrict__ pq)
{
    __shared__ unsigned short A_s[128 * 128];   // [k][m] 32 KB
    __shared__ unsigned short W_s[128 * 128];   // [k][c] 32 KB

    const int t     = threadIdx.x;
    const int m0    = blockIdx.x * 128;
    const int chunk = blockIdx.y;
    const float* W  = chunk ? W1r : W1l;

    // stage A transposed: thread -> row mloc, k-half
    {
        const int mloc = t & 127;
        const int kc   = (t >> 7) * 64;
        const int m    = m0 + mloc;
        #pragma unroll
        for (int j = 0; j < 8; ++j) {
            const int k = kc + j * 8;
            uint4 u = make_uint4(0u, 0u, 0u, 0u);
            if (m < NN) u = *(const uint4*)(xb + (size_t)m * F + k);
            A_s[(k + 0) * 128 + mloc] = (unsigned short)(u.x & 0xffffu);
            A_s[(k + 1) * 128 + mloc] = (unsigned short)(u.x >> 16);
            A_s[(k + 2) * 128 + mloc] = (unsigned short)(u.y & 0xffffu);
            A_s[(k + 3) * 128 + mloc] = (unsigned short)(u.y >> 16);
            A_s[(k + 4) * 128 + mloc] = (unsigned short)(u.z & 0xffffu);
            A_s[(k + 5) * 128 + mloc] = (unsigned short)(u.z >> 16);
            A_s[(k + 6) * 128 + mloc] = (unsigned short)(u.w & 0xffffu);
            A_s[(k + 7) * 128 + mloc] = (unsigned short)(u.w >> 16);
        }
    }
    // stage W (natural layout), fp32 -> bf16
    #pragma unroll
    for (int rr = 0; rr < 16; ++rr) {
        const int f4 = rr * 256 + t;             // float4 index, 4096 total
        const int k  = f4 >> 5;
        const int c  = (f4 << 2) & 127;
        const float4 w = ((const float4*)W)[f4];
        uint2 o;
        o.x = pack2(w.x, w.y);
        o.y = pack2(w.z, w.w);
        *(uint2*)&W_s[k * 128 + c] = o;
    }
    __syncthreads();

    const int mq = t & 15;       // 16 m-quads of 8 rows
    const int nq = t >> 4;       // 16 n-quads of 8 cols
    float acc[8][8];
    #pragma unroll
    for (int i = 0; i < 8; ++i)
        #pragma unroll
        for (int j = 0; j < 8; ++j) acc[i][j] = 0.0f;

    #pragma unroll 4
    for (int k = 0; k < 128; ++k) {
        const uint4 ua = *(const uint4*)&A_s[k * 128 + mq * 8];
        const uint4 uw = *(const uint4*)&W_s[k * 128 + nq * 8];
        float a[8], w[8];
        unpack2(ua.x, a[0], a[1]); unpack2(ua.y, a[2], a[3]);
        unpack2(ua.z, a[4], a[5]); unpack2(ua.w, a[6], a[7]);
        unpack2(uw.x, w[0], w[1]); unpack2(uw.y, w[2], w[3]);
        unpack2(uw.z, w[4], w[5]); unpack2(uw.w, w[6], w[7]);
        #pragma unroll
        for (int i = 0; i < 8; ++i)
            #pragma unroll
            for (int j = 0; j < 8; ++j)
                acc[i][j] += a[i] * w[j];
    }

    float bc[8];
    #pragma unroll
    for (int j = 0; j < 8; ++j) bc[j] = chunk ? b1[nq * 8 + j] : 0.0f;

    #pragma unroll
    for (int i = 0; i < 8; ++i) {
        const int m = m0 + mq * 8 + i;
        if (m < NN) {
            uint4 o;
            o.x = pack2(acc[i][0] + bc[0], acc[i][1] + bc[1]);
            o.y = pack2(acc[i][2] + bc[2], acc[i][3] + bc[3]);
            o.z = pack2(acc[i][4] + bc[4], acc[i][5] + bc[5]);
            o.w = pack2(acc[i][6] + bc[6], acc[i][7] + bc[7]);
            *(uint4*)(pq + (size_t)m * 256 + chunk * 128 + nq * 8) = o;
        }
    }
}

// ---------------------------------------------------------------------------
// agg1: hb[n] = bf16( relu( mean_j p[j] + q[n] ) ), gather 256 B bf16 rows.
// 32 lanes per node, lane covers 4 cols; unroll x4.
// ---------------------------------------------------------------------------
__global__ __launch_bounds__(256) void agg1_kernel(
    const unsigned short* __restrict__ pq, const int* __restrict__ eidx,
    const int* __restrict__ rowptr, const int* __restrict__ cnt,
    const float* __restrict__ invdeg, unsigned short* __restrict__ hb)
{
    const int lane = threadIdx.x & 31;
    const int sub  = threadIdx.x >> 5;
    const int n    = blockIdx.x * 8 + sub;
    if (n >= NN) return;
    const int col2 = lane * 4;                  // ushort index into p-half

    const int start = rowptr[n];
    const int len   = cnt[n];
    float4 a0 = make_float4(0.f, 0.f, 0.f, 0.f);
    float4 a1 = a0, a2 = a0, a3 = a0;
    int i = 0;
    for (; i + 4 <= len; i += 4) {
        const int s0 = eidx[start + i + 0];
        const int s1 = eidx[start + i + 1];
        const int s2 = eidx[start + i + 2];
        const int s3 = eidx[start + i + 3];
        const uint2 u0 = *(const uint2*)(pq + (size_t)s0 * 256 + col2);
        const uint2 u1 = *(const uint2*)(pq + (size_t)s1 * 256 + col2);
        const uint2 u2 = *(const uint2*)(pq + (size_t)s2 * 256 + col2);
        const uint2 u3 = *(const uint2*)(pq + (size_t)s3 * 256 + col2);
        float f0, f1, f2, f3;
        unpack2(u0.x, f0, f1); unpack2(u0.y, f2, f3);
        a0.x += f0; a0.y += f1; a0.z += f2; a0.w += f3;
        unpack2(u1.x, f0, f1); unpack2(u1.y, f2, f3);
        a1.x += f0; a1.y += f1; a1.z += f2; a1.w += f3;
        unpack2(u2.x, f0, f1); unpack2(u2.y, f2, f3);
        a2.x += f0; a2.y += f1; a2.z += f2; a2.w += f3;
        unpack2(u3.x, f0, f1); unpack2(u3.y, f2, f3);
        a3.x += f0; a3.y += f1; a3.z += f2; a3.w += f3;
    }
    for (; i < len; ++i) {
        const int s = eidx[start + i];
        const uint2 u = *(const uint2*)(pq + (size_t)s * 256 + col2);
        float f0, f1, f2, f3;
        unpack2(u.x, f0, f1); unpack2(u.y, f2, f3);
        a0.x += f0; a0.y += f1; a0.z += f2; a0.w += f3;
    }
    const float inv = invdeg[n];
    const uint2 uq = *(const uint2*)(pq + (size_t)n * 256 + 128 + col2);
    float q0, q1, q2, q3;
    unpack2(uq.x, q0, q1); unpack2(uq.y, q2, q3);
    const float h0 = fmaxf((a0.x + a1.x + a2.x + a3.x) * inv + q0, 0.0f);
    const float h1 = fmaxf((a0.y + a1.y + a2.y + a3.y) * inv + q1, 0.0f);
    const float h2 = fmaxf((a0.z + a1.z + a2.z + a3.z) * inv + q2, 0.0f);
    const float h3 = fmaxf((a0.w + a1.w + a2.w + a3.w) * inv + q3, 0.0f);
    uint2 o;
    o.x = pack2(h0, h1);
    o.y = pack2(h2, h3);
    *(uint2*)(hb + (size_t)n * F + col2) = o;
}

// ---------------------------------------------------------------------------
// pre2: [z | r] = hb @ [W2l | W2r]; z bf16 [NN][16] (cols>=14 zero),
// r fp32 [NN][16] with bias. M_TILE=128, per-thread 4x4 tile.
// ---------------------------------------------------------------------------
__global__ __launch_bounds__(256, 2) void pre2_kernel(
    const unsigned short* __restrict__ hb,
    const float* __restrict__ W2l, const float* __restrict__ W2r,
    const float* __restrict__ b2,
    unsigned short* __restrict__ z, float* __restrict__ r)
{
    __shared__ unsigned short A_s[128 * 128];   // [k][m] 32 KB
    __shared__ unsigned short W_s[128 * 32];    // [k][c] 8 KB

    const int t  = threadIdx.x;
    const int m0 = blockIdx.x * 128;

    {
        const int mloc = t & 127;
        const int kc   = (t >> 7) * 64;
        const int m    = m0 + mloc;
        #pragma unroll
        for (int j = 0; j < 8; ++j) {
            const int k = kc + j * 8;
            uint4 u = make_uint4(0u, 0u, 0u, 0u);
            if (m < NN) u = *(const uint4*)(hb + (size_t)m * F + k);
            A_s[(k + 0) * 128 + mloc] = (unsigned short)(u.x & 0xffffu);
            A_s[(k + 1) * 128 + mloc] = (unsigned short)(u.x >> 16);
            A_s[(k + 2) * 128 + mloc] = (unsigned short)(u.y & 0xffffu);
            A_s[(k + 3) * 128 + mloc] = (unsigned short)(u.y >> 16);
            A_s[(k + 4) * 128 + mloc] = (unsigned short)(u.z & 0xffffu);
            A_s[(k + 5) * 128 + mloc] = (unsigned short)(u.z >> 16);
            A_s[(k + 6) * 128 + mloc] = (unsigned short)(u.w & 0xffffu);
            A_s[(k + 7) * 128 + mloc] = (unsigned short)(u.w >> 16);
        }
    }
    #pragma unroll
    for (int rr = 0; rr < 16; ++rr) {
        const int idx = rr * 256 + t;            // 4096 elems
        const int k = idx >> 5;
        const int c = idx & 31;
        float wv = 0.0f;
        if (c < 16) { if (c < C_OUT) wv = W2l[k * C_OUT + c]; }
        else        { if (c - 16 < C_OUT) wv = W2r[k * C_OUT + (c - 16)]; }
        W_s[k * 32 + c] = f2bf(wv);
    }
    __syncthreads();

    const int mq = t & 31;       // 32 m-quads of 4 rows
    const int nq = t >> 5;       // 8 n-quads of 4 cols
    float acc[4][4];
    #pragma unroll
    for (int i = 0; i < 4; ++i)
        #pragma unroll
        for (int j = 0; j < 4; ++j) acc[i][j] = 0.0f;

    #pragma unroll 4
    for (int k = 0; k < 128; ++k) {
        const uint2 ua = *(const uint2*)&A_s[k * 128 + mq * 4];
        const uint2 uw = *(const uint2*)&W_s[k * 32 + nq * 4];
        float a[4], w[4];
        unpack2(ua.x, a[0], a[1]); unpack2(ua.y, a[2], a[3]);
        unpack2(uw.x, w[0], w[1]); unpack2(uw.y, w[2], w[3]);
        #pragma unroll
        for (int i = 0; i < 4; ++i)
            #pragma unroll
            for (int j = 0; j < 4; ++j)
                acc[i][j] += a[i] * w[j];
    }

    const int c0 = nq * 4;
    #pragma unroll
    for (int i = 0; i < 4; ++i) {
        const int m = m0 + mq * 4 + i;
        if (m < NN) {
            if (nq < 4) {               // z cols
                uint2 o;
                o.x = pack2(acc[i][0], acc[i][1]);
                o.y = pack2(acc[i][2], acc[i][3]);
                *(uint2*)(z + (size_t)m * ZP + c0) = o;
            } else {                    // r cols
                const int rc = c0 - 16;
                float4 o;
                o.x = acc[i][0] + ((rc + 0 < C_OUT) ? b2[rc + 0] : 0.0f);
                o.y = acc[i][1] + ((rc + 1 < C_OUT) ? b2[rc + 1] : 0.0f);
                o.z = acc[i][2] + ((rc + 2 < C_OUT) ? b2[rc + 2] : 0.0f);
                o.w = acc[i][3] + ((rc + 3 < C_OUT) ? b2[rc + 3] : 0.0f);
                *(float4*)(r + (size_t)m * ZP + rc) = o;
            }
        }
    }
}

// ---------------------------------------------------------------------------
// agg2: out = log_softmax_segments( mean-agg(z) + r ). z rows 32 B bf16.
// ---------------------------------------------------------------------------
__global__ __launch_bounds__(256) void agg2_kernel(
    const unsigned short* __restrict__ z, const float* __restrict__ r,
    const int* __restrict__ eidx, const int* __restrict__ rowptr,
    const int* __restrict__ cnt, const float* __restrict__ invdeg,
    const int* __restrict__ sf_ptr, float* __restrict__ out)
{
    __shared__ float sm[64][ZP + 1];

    const int lane4 = threadIdx.x & 3;
    const int slot  = threadIdx.x >> 2;
    const int n     = blockIdx.x * 64 + slot;
    const int j4    = lane4 * 4;

    if (n < NN) {
        const int start = rowptr[n];
        const int len   = cnt[n];
        float4 a0 = make_float4(0.f, 0.f, 0.f, 0.f);
        float4 a1 = a0, a2 = a0, a3 = a0;
        int i = 0;
        for (; i + 4 <= len; i += 4) {
            const int s0 = eidx[start + i + 0];
            const int s1 = eidx[start + i + 1];
            const int s2 = eidx[start + i + 2];
            const int s3 = eidx[start + i + 3];
            const uint2 u0 = *(const uint2*)(z + (size_t)s0 * ZP + j4);
            const uint2 u1 = *(const uint2*)(z + (size_t)s1 * ZP + j4);
            const uint2 u2 = *(const uint2*)(z + (size_t)s2 * ZP + j4);
            const uint2 u3 = *(const uint2*)(z + (size_t)s3 * ZP + j4);
            float f0, f1, f2, f3;
            unpack2(u0.x, f0, f1); unpack2(u0.y, f2, f3);
            a0.x += f0; a0.y += f1; a0.z += f2; a0.w += f3;
            unpack2(u1.x, f0, f1); unpack2(u1.y, f2, f3);
            a1.x += f0; a1.y += f1; a1.z += f2; a1.w += f3;
            unpack2(u2.x, f0, f1); unpack2(u2.y, f2, f3);
            a2.x += f0; a2.y += f1; a2.z += f2; a2.w += f3;
            unpack2(u3.x, f0, f1); unpack2(u3.y, f2, f3);
            a3.x += f0; a3.y += f1; a3.z += f2; a3.w += f3;
        }
        for (; i < len; ++i) {
            const int s = eidx[start + i];
            const uint2 u = *(const uint2*)(z + (size_t)s * ZP + j4);
            float f0, f1, f2, f3;
            unpack2(u.x, f0, f1); unpack2(u.y, f2, f3);
            a0.x += f0; a0.y += f1; a0.z += f2; a0.w += f3;
        }
        const float inv = invdeg[n];
        const float4 rv = *(const float4*)(r + (size_t)n * ZP + j4);
        sm[slot][j4 + 0] = (a0.x + a1.x + a2.x + a3.x) * inv + rv.x;
        sm[slot][j4 + 1] = (a0.y + a1.y + a2.y + a3.y) * inv + rv.y;
        sm[slot][j4 + 2] = (a0.z + a1.z + a2.z + a3.z) * inv + rv.z;
        sm[slot][j4 + 3] = (a0.w + a1.w + a2.w + a3.w) * inv + rv.w;
    }
    __syncthreads();

    if (threadIdx.x < 64) {
        const int n2 = blockIdx.x * 64 + threadIdx.x;
        if (n2 < NN) {
            const int sf = *sf_ptr;
            const float* row = sm[threadIdx.x];
            float m = -1e30f;
            for (int c = 0; c < sf; ++c) m = fmaxf(m, row[c]);
            float s = 0.0f;
            for (int c = 0; c < sf; ++c) s += expf(row[c] - m);
            float ls = m + logf(s);
            for (int c = 0; c < sf; ++c)
                out[(long long)n2 * sf + c] = row[c] - ls;
            m = -1e30f;
            for (int c = sf; c < C_OUT; ++c) m = fmaxf(m, row[c]);
            s = 0.0f;
            for (int c = sf; c < C_OUT; ++c) s += expf(row[c] - m);
            ls = m + logf(s);
            const int pt = C_OUT - sf;
            for (int c = sf; c < C_OUT; ++c)
                out[(long long)NN * sf + (long long)n2 * pt + (c - sf)] = row[c] - ls;
        }
    }
}

// ---------------------------------------------------------------------------
extern "C" void kernel_launch(void* const* d_in, const int* in_sizes, int n_in,
                              void* d_out, int out_size, void* d_ws, size_t ws_size,
                              hipStream_t stream)
{
    const float* x   = (const float*)d_in[0];
    const int*   ei  = (const int*)d_in[1];
    const int*   sfp = (const int*)d_in[2];
    const float* W1l = (const float*)d_in[3];
    const float* W1r = (const float*)d_in[4];
    const float* b1  = (const float*)d_in[5];
    const float* W2l = (const float*)d_in[6];
    const float* W2r = (const float*)d_in[7];
    const float* b2  = (const float*)d_in[8];
    float*       out = (float*)d_out;

    const int E  = in_sizes[1] / 2;
    const int E4 = (E + 3) & ~3;
    const int* src = ei;
    const int* dst = ei + E;

    // ws layout (words), with aliasing: hb over xb, z/r over pq.
    int*   cnt      = (int*)d_ws;                          // NN
    int*   rowptr   = cnt + NN;                            // NN
    int*   cursor   = rowptr + NN;                         // NN
    float* invdeg   = (float*)(cursor + NN);               // NN
    int*   blocksum = (int*)(invdeg + NN);                 // 128
    int*   eidx     = blocksum + 128;                      // E4
    unsigned short* xb = (unsigned short*)(eidx + E4);     // NN*F bf16 (25.6 MB)
    unsigned short* pq = xb + (size_t)NN * F;              // NN*256 bf16 (51.2 MB)
    unsigned short* hb = xb;                               // alias (xb dead after pre1)
    unsigned short* z  = pq;                               // alias (pq dead after agg1)
    float*          r  = (float*)(pq + (size_t)NN * ZP);   // after z

    hipMemsetAsync(cnt, 0, (size_t)NN * sizeof(int), stream);

    const int eblocks = (E + 255) / 256;
    const int nblocks = (NN + 255) / 256;

    // CSR build
    hist_kernel      <<<eblocks, 256, 0, stream>>>(dst, cnt, E);
    scan_local_kernel<<<NBLK,    256, 0, stream>>>(cnt, rowptr, blocksum);
    scan_block_kernel<<<1,       128, 0, stream>>>(blocksum);
    finalize_kernel  <<<nblocks, 256, 0, stream>>>(cnt, rowptr, cursor, invdeg, blocksum);
    fill_kernel      <<<eblocks, 256, 0, stream>>>(src, dst, cursor, eidx, E);

    // x -> bf16
    cvt_kernel<<<(NN * F / 4 + 255) / 256, 256, 0, stream>>>(x, xb);

    // layer 1 (commuted): pq = [x@W1l | x@W1r+b1], then gather-mean + relu
    dim3 g1((NN + 127) / 128, 2);
    pre1_kernel<<<g1, 256, 0, stream>>>(xb, W1l, W1r, b1, pq);
    agg1_kernel<<<(NN + 7) / 8, 256, 0, stream>>>(pq, eidx, rowptr, cnt, invdeg, hb);

    // layer 2 (commuted): [z|r] = hb@[W2l|W2r], then gather-mean + softmax
    pre2_kernel<<<(NN + 127) / 128, 256, 0, stream>>>(hb, W2l, W2r, b2, z, r);
    agg2_kernel<<<(NN + 63) / 64, 256, 0, stream>>>(z, r, eidx, rowptr, cnt, invdeg,
                                                    sfp, out);
}

// Round 5
// 456.286 us; speedup vs baseline: 13.1106x; 1.1133x over previous
//
#include <hip/hip_runtime.h>
#include <hip/hip_bf16.h>

#define NN 100000
#define F 128
#define C_OUT 14
#define ZP 16
#define SCAN_CHUNK 1024
#define NBLK ((NN + SCAN_CHUNK - 1) / SCAN_CHUNK)   // 98 blocks
#define NPART 8
#define PART_SZ ((NN + NPART - 1) / NPART)          // 12500

// ---------------- bf16 helpers (manual, zero API risk) ----------------------
static __device__ __forceinline__ unsigned short f2bf(float f) {
    unsigned int u = __float_as_uint(f);
    unsigned int r = (u + 0x7fffu + ((u >> 16) & 1u)) >> 16;   // RTN-even
    return (unsigned short)r;
}
static __device__ __forceinline__ unsigned int pack2(float a, float b) {
    return (unsigned int)f2bf(a) | ((unsigned int)f2bf(b) << 16);
}
static __device__ __forceinline__ void unpack2(unsigned int u, float& lo, float& hi) {
    lo = __uint_as_float(u << 16);
    hi = __uint_as_float(u & 0xffff0000u);
}

// ---------------------------- CSR build ------------------------------------
// hist/fill are dst-range partitioned: block handles (part = blockIdx&7,
// chunk = blockIdx>>3) and only touches nodes in its partition. With the
// blockIdx%8 -> XCD round-robin heuristic, each partition's cnt/cursor/eidx
// region (0.8 MB) stays in ONE XCD's L2 and is written back once (R4 showed
// 105 MB HBM write traffic for 6.4 MB of eidx data without this).
// ---------------------------------------------------------------------------
__global__ __launch_bounds__(256) void hist_kernel(
    const int* __restrict__ dst, int* __restrict__ cnt, int E)
{
    const int part = blockIdx.x & (NPART - 1);
    const int lo   = part * PART_SZ;
    const int hi   = min(lo + PART_SZ, NN);
    const int e0   = ((blockIdx.x >> 3) * 256 + threadIdx.x) * 4;
    if (e0 + 3 < E) {
        const int4 d = *(const int4*)(dst + e0);
        if (d.x >= lo && d.x < hi) atomicAdd(&cnt[d.x], 1);
        if (d.y >= lo && d.y < hi) atomicAdd(&cnt[d.y], 1);
        if (d.z >= lo && d.z < hi) atomicAdd(&cnt[d.z], 1);
        if (d.w >= lo && d.w < hi) atomicAdd(&cnt[d.w], 1);
    } else {
        for (int e = e0; e < E; ++e) {
            const int d = dst[e];
            if (d >= lo && d < hi) atomicAdd(&cnt[d], 1);
        }
    }
}

__global__ __launch_bounds__(256) void scan_local_kernel(
    const int* __restrict__ cnt, int* __restrict__ rowptr,
    int* __restrict__ blocksum)
{
    __shared__ int sm[256];
    const int tid  = threadIdx.x;
    const int base = blockIdx.x * SCAN_CHUNK + tid * 4;
    int v0 = (base + 0 < NN) ? cnt[base + 0] : 0;
    int v1 = (base + 1 < NN) ? cnt[base + 1] : 0;
    int v2 = (base + 2 < NN) ? cnt[base + 2] : 0;
    int v3 = (base + 3 < NN) ? cnt[base + 3] : 0;
    const int t = v0 + v1 + v2 + v3;
    sm[tid] = t;
    __syncthreads();
    int acc = t;
    for (int off = 1; off < 256; off <<= 1) {
        int other = (tid >= off) ? sm[tid - off] : 0;
        __syncthreads();
        acc += other;
        sm[tid] = acc;
        __syncthreads();
    }
    const int excl = acc - t;
    if (base + 0 < NN) rowptr[base + 0] = excl;
    if (base + 1 < NN) rowptr[base + 1] = excl + v0;
    if (base + 2 < NN) rowptr[base + 2] = excl + v0 + v1;
    if (base + 3 < NN) rowptr[base + 3] = excl + v0 + v1 + v2;
    if (tid == 255) blocksum[blockIdx.x] = acc;
}

__global__ __launch_bounds__(128) void scan_block_kernel(int* __restrict__ blocksum)
{
    __shared__ int sm[128];
    const int tid = threadIdx.x;
    const int v = (tid < NBLK) ? blocksum[tid] : 0;
    sm[tid] = v;
    __syncthreads();
    int acc = v;
    for (int off = 1; off < 128; off <<= 1) {
        int other = (tid >= off) ? sm[tid - off] : 0;
        __syncthreads();
        acc += other;
        sm[tid] = acc;
        __syncthreads();
    }
    if (tid < NBLK) blocksum[tid] = acc - v;
}

__global__ __launch_bounds__(256) void finalize_kernel(
    const int* __restrict__ cnt, int* __restrict__ rowptr,
    int* __restrict__ cursor, float* __restrict__ invdeg,
    const int* __restrict__ blocksum)
{
    int i = blockIdx.x * 256 + threadIdx.x;
    if (i >= NN) return;
    int r = rowptr[i] + blocksum[i / SCAN_CHUNK];
    rowptr[i] = r;
    cursor[i] = r;
    invdeg[i] = 1.0f / (float)max(cnt[i], 1);
}

__global__ __launch_bounds__(256) void fill_kernel(
    const int* __restrict__ src, const int* __restrict__ dst,
    int* __restrict__ cursor, int* __restrict__ eidx, int E)
{
    const int part = blockIdx.x & (NPART - 1);
    const int lo   = part * PART_SZ;
    const int hi   = min(lo + PART_SZ, NN);
    const int e0   = ((blockIdx.x >> 3) * 256 + threadIdx.x) * 4;
    if (e0 + 3 < E) {
        const int4 d = *(const int4*)(dst + e0);
        if (d.x >= lo && d.x < hi) { int p = atomicAdd(&cursor[d.x], 1); eidx[p] = src[e0 + 0]; }
        if (d.y >= lo && d.y < hi) { int p = atomicAdd(&cursor[d.y], 1); eidx[p] = src[e0 + 1]; }
        if (d.z >= lo && d.z < hi) { int p = atomicAdd(&cursor[d.z], 1); eidx[p] = src[e0 + 2]; }
        if (d.w >= lo && d.w < hi) { int p = atomicAdd(&cursor[d.w], 1); eidx[p] = src[e0 + 3]; }
    } else {
        for (int e = e0; e < E; ++e) {
            const int d = dst[e];
            if (d >= lo && d < hi) { int p = atomicAdd(&cursor[d], 1); eidx[p] = src[e]; }
        }
    }
}

// ---------------------------------------------------------------------------
// pre1: pq = [ x@W1l | x@W1r + b1 ]  (bf16 out, [NN][256]).
// Reads x in fp32 and converts during LDS staging (cvt kernel folded in).
// blockIdx.y = chunk (0 -> W1l cols, 1 -> W1r + b1).
// M_TILE=128, per-thread 8x8 register tile; A_s [k][m], W_s [k][c]; 64 KB.
// ---------------------------------------------------------------------------
__global__ __launch_bounds__(256, 2) void pre1_kernel(
    const float* __restrict__ x,
    const float* __restrict__ W1l, const float* __restrict__ W1r,
    const float* __restrict__ b1, unsigned short* __restrict__ pq)
{
    __shared__ unsigned short A_s[128 * 128];   // [k][m] 32 KB
    __shared__ unsigned short W_s[128 * 128];   // [k][c] 32 KB

    const int t     = threadIdx.x;
    const int m0    = blockIdx.x * 128;
    const int chunk = blockIdx.y;
    const float* W  = chunk ? W1r : W1l;

    // stage A transposed (fp32 -> bf16): thread -> row mloc, k-half
    {
        const int mloc = t & 127;
        const int kc   = (t >> 7) * 64;
        const int m    = m0 + mloc;
        #pragma unroll
        for (int j = 0; j < 8; ++j) {
            const int k = kc + j * 8;
            float4 f0 = make_float4(0.f, 0.f, 0.f, 0.f), f1 = f0;
            if (m < NN) {
                f0 = *(const float4*)(x + (size_t)m * F + k);
                f1 = *(const float4*)(x + (size_t)m * F + k + 4);
            }
            A_s[(k + 0) * 128 + mloc] = f2bf(f0.x);
            A_s[(k + 1) * 128 + mloc] = f2bf(f0.y);
            A_s[(k + 2) * 128 + mloc] = f2bf(f0.z);
            A_s[(k + 3) * 128 + mloc] = f2bf(f0.w);
            A_s[(k + 4) * 128 + mloc] = f2bf(f1.x);
            A_s[(k + 5) * 128 + mloc] = f2bf(f1.y);
            A_s[(k + 6) * 128 + mloc] = f2bf(f1.z);
            A_s[(k + 7) * 128 + mloc] = f2bf(f1.w);
        }
    }
    // stage W (natural layout), fp32 -> bf16
    #pragma unroll
    for (int rr = 0; rr < 16; ++rr) {
        const int f4 = rr * 256 + t;             // float4 index, 4096 total
        const int k  = f4 >> 5;
        const int c  = (f4 << 2) & 127;
        const float4 w = ((const float4*)W)[f4];
        uint2 o;
        o.x = pack2(w.x, w.y);
        o.y = pack2(w.z, w.w);
        *(uint2*)&W_s[k * 128 + c] = o;
    }
    __syncthreads();

    const int mq = t & 15;       // 16 m-quads of 8 rows
    const int nq = t >> 4;       // 16 n-quads of 8 cols
    float acc[8][8];
    #pragma unroll
    for (int i = 0; i < 8; ++i)
        #pragma unroll
        for (int j = 0; j < 8; ++j) acc[i][j] = 0.0f;

    #pragma unroll 4
    for (int k = 0; k < 128; ++k) {
        const uint4 ua = *(const uint4*)&A_s[k * 128 + mq * 8];
        const uint4 uw = *(const uint4*)&W_s[k * 128 + nq * 8];
        float a[8], w[8];
        unpack2(ua.x, a[0], a[1]); unpack2(ua.y, a[2], a[3]);
        unpack2(ua.z, a[4], a[5]); unpack2(ua.w, a[6], a[7]);
        unpack2(uw.x, w[0], w[1]); unpack2(uw.y, w[2], w[3]);
        unpack2(uw.z, w[4], w[5]); unpack2(uw.w, w[6], w[7]);
        #pragma unroll
        for (int i = 0; i < 8; ++i)
            #pragma unroll
            for (int j = 0; j < 8; ++j)
                acc[i][j] += a[i] * w[j];
    }

    float bc[8];
    #pragma unroll
    for (int j = 0; j < 8; ++j) bc[j] = chunk ? b1[nq * 8 + j] : 0.0f;

    #pragma unroll
    for (int i = 0; i < 8; ++i) {
        const int m = m0 + mq * 8 + i;
        if (m < NN) {
            uint4 o;
            o.x = pack2(acc[i][0] + bc[0], acc[i][1] + bc[1]);
            o.y = pack2(acc[i][2] + bc[2], acc[i][3] + bc[3]);
            o.z = pack2(acc[i][4] + bc[4], acc[i][5] + bc[5]);
            o.w = pack2(acc[i][6] + bc[6], acc[i][7] + bc[7]);
            *(uint4*)(pq + (size_t)m * 256 + chunk * 128 + nq * 8) = o;
        }
    }
}

// ---------------------------------------------------------------------------
// agg1: hb[n] = bf16( relu( mean_j p[j] + q[n] ) ).
// 16 lanes per node (uint4 = 16 B/lane, coalescing sweet spot), 16 nodes
// per block; gather unrolled x4 for MLP.
// ---------------------------------------------------------------------------
__global__ __launch_bounds__(256) void agg1_kernel(
    const unsigned short* __restrict__ pq, const int* __restrict__ eidx,
    const int* __restrict__ rowptr, const int* __restrict__ cnt,
    const float* __restrict__ invdeg, unsigned short* __restrict__ hb)
{
    const int lane = threadIdx.x & 15;
    const int sub  = threadIdx.x >> 4;
    const int n    = blockIdx.x * 16 + sub;
    if (n >= NN) return;
    const int col = lane * 8;                   // ushort index, 8 shorts/lane

    const int start = rowptr[n];
    const int len   = cnt[n];
    float a0[8] = {0,0,0,0,0,0,0,0};
    float a1[8] = {0,0,0,0,0,0,0,0};
    float a2[8] = {0,0,0,0,0,0,0,0};
    float a3[8] = {0,0,0,0,0,0,0,0};
    int i = 0;
    for (; i + 4 <= len; i += 4) {
        const int s0 = eidx[start + i + 0];
        const int s1 = eidx[start + i + 1];
        const int s2 = eidx[start + i + 2];
        const int s3 = eidx[start + i + 3];
        const uint4 u0 = *(const uint4*)(pq + (size_t)s0 * 256 + col);
        const uint4 u1 = *(const uint4*)(pq + (size_t)s1 * 256 + col);
        const uint4 u2 = *(const uint4*)(pq + (size_t)s2 * 256 + col);
        const uint4 u3 = *(const uint4*)(pq + (size_t)s3 * 256 + col);
        float f0, f1;
        unpack2(u0.x, f0, f1); a0[0] += f0; a0[1] += f1;
        unpack2(u0.y, f0, f1); a0[2] += f0; a0[3] += f1;
        unpack2(u0.z, f0, f1); a0[4] += f0; a0[5] += f1;
        unpack2(u0.w, f0, f1); a0[6] += f0; a0[7] += f1;
        unpack2(u1.x, f0, f1); a1[0] += f0; a1[1] += f1;
        unpack2(u1.y, f0, f1); a1[2] += f0; a1[3] += f1;
        unpack2(u1.z, f0, f1); a1[4] += f0; a1[5] += f1;
        unpack2(u1.w, f0, f1); a1[6] += f0; a1[7] += f1;
        unpack2(u2.x, f0, f1); a2[0] += f0; a2[1] += f1;
        unpack2(u2.y, f0, f1); a2[2] += f0; a2[3] += f1;
        unpack2(u2.z, f0, f1); a2[4] += f0; a2[5] += f1;
        unpack2(u2.w, f0, f1); a2[6] += f0; a2[7] += f1;
        unpack2(u3.x, f0, f1); a3[0] += f0; a3[1] += f1;
        unpack2(u3.y, f0, f1); a3[2] += f0; a3[3] += f1;
        unpack2(u3.z, f0, f1); a3[4] += f0; a3[5] += f1;
        unpack2(u3.w, f0, f1); a3[6] += f0; a3[7] += f1;
    }
    for (; i < len; ++i) {
        const int s = eidx[start + i];
        const uint4 u = *(const uint4*)(pq + (size_t)s * 256 + col);
        float f0, f1;
        unpack2(u.x, f0, f1); a0[0] += f0; a0[1] += f1;
        unpack2(u.y, f0, f1); a0[2] += f0; a0[3] += f1;
        unpack2(u.z, f0, f1); a0[4] += f0; a0[5] += f1;
        unpack2(u.w, f0, f1); a0[6] += f0; a0[7] += f1;
    }
    const float inv = invdeg[n];
    const uint4 uq = *(const uint4*)(pq + (size_t)n * 256 + 128 + col);
    float q[8];
    unpack2(uq.x, q[0], q[1]); unpack2(uq.y, q[2], q[3]);
    unpack2(uq.z, q[4], q[5]); unpack2(uq.w, q[6], q[7]);
    float hv[8];
    #pragma unroll
    for (int j = 0; j < 8; ++j)
        hv[j] = fmaxf((a0[j] + a1[j] + a2[j] + a3[j]) * inv + q[j], 0.0f);
    uint4 o;
    o.x = pack2(hv[0], hv[1]);
    o.y = pack2(hv[2], hv[3]);
    o.z = pack2(hv[4], hv[5]);
    o.w = pack2(hv[6], hv[7]);
    *(uint4*)(hb + (size_t)n * F + col) = o;
}

// ---------------------------------------------------------------------------
// pre2: [z | r] = hb @ [W2l | W2r]; z bf16 [NN][16] (cols>=14 zero),
// r fp32 [NN][16] with bias. M_TILE=128, per-thread 4x4 tile.
// ---------------------------------------------------------------------------
__global__ __launch_bounds__(256, 2) void pre2_kernel(
    const unsigned short* __restrict__ hb,
    const float* __restrict__ W2l, const float* __restrict__ W2r,
    const float* __restrict__ b2,
    unsigned short* __restrict__ z, float* __restrict__ r)
{
    __shared__ unsigned short A_s[128 * 128];   // [k][m] 32 KB
    __shared__ unsigned short W_s[128 * 32];    // [k][c] 8 KB

    const int t  = threadIdx.x;
    const int m0 = blockIdx.x * 128;

    {
        const int mloc = t & 127;
        const int kc   = (t >> 7) * 64;
        const int m    = m0 + mloc;
        #pragma unroll
        for (int j = 0; j < 8; ++j) {
            const int k = kc + j * 8;
            uint4 u = make_uint4(0u, 0u, 0u, 0u);
            if (m < NN) u = *(const uint4*)(hb + (size_t)m * F + k);
            A_s[(k + 0) * 128 + mloc] = (unsigned short)(u.x & 0xffffu);
            A_s[(k + 1) * 128 + mloc] = (unsigned short)(u.x >> 16);
            A_s[(k + 2) * 128 + mloc] = (unsigned short)(u.y & 0xffffu);
            A_s[(k + 3) * 128 + mloc] = (unsigned short)(u.y >> 16);
            A_s[(k + 4) * 128 + mloc] = (unsigned short)(u.z & 0xffffu);
            A_s[(k + 5) * 128 + mloc] = (unsigned short)(u.z >> 16);
            A_s[(k + 6) * 128 + mloc] = (unsigned short)(u.w & 0xffffu);
            A_s[(k + 7) * 128 + mloc] = (unsigned short)(u.w >> 16);
        }
    }
    #pragma unroll
    for (int rr = 0; rr < 16; ++rr) {
        const int idx = rr * 256 + t;            // 4096 elems
        const int k = idx >> 5;
        const int c = idx & 31;
        float wv = 0.0f;
        if (c < 16) { if (c < C_OUT) wv = W2l[k * C_OUT + c]; }
        else        { if (c - 16 < C_OUT) wv = W2r[k * C_OUT + (c - 16)]; }
        W_s[k * 32 + c] = f2bf(wv);
    }
    __syncthreads();

    const int mq = t & 31;       // 32 m-quads of 4 rows
    const int nq = t >> 5;       // 8 n-quads of 4 cols
    float acc[4][4];
    #pragma unroll
    for (int i = 0; i < 4; ++i)
        #pragma unroll
        for (int j = 0; j < 4; ++j) acc[i][j] = 0.0f;

    #pragma unroll 4
    for (int k = 0; k < 128; ++k) {
        const uint2 ua = *(const uint2*)&A_s[k * 128 + mq * 4];
        const uint2 uw = *(const uint2*)&W_s[k * 32 + nq * 4];
        float a[4], w[4];
        unpack2(ua.x, a[0], a[1]); unpack2(ua.y, a[2], a[3]);
        unpack2(uw.x, w[0], w[1]); unpack2(uw.y, w[2], w[3]);
        #pragma unroll
        for (int i = 0; i < 4; ++i)
            #pragma unroll
            for (int j = 0; j < 4; ++j)
                acc[i][j] += a[i] * w[j];
    }

    const int c0 = nq * 4;
    #pragma unroll
    for (int i = 0; i < 4; ++i) {
        const int m = m0 + mq * 4 + i;
        if (m < NN) {
            if (nq < 4) {               // z cols
                uint2 o;
                o.x = pack2(acc[i][0], acc[i][1]);
                o.y = pack2(acc[i][2], acc[i][3]);
                *(uint2*)(z + (size_t)m * ZP + c0) = o;
            } else {                    // r cols
                const int rc = c0 - 16;
                float4 o;
                o.x = acc[i][0] + ((rc + 0 < C_OUT) ? b2[rc + 0] : 0.0f);
                o.y = acc[i][1] + ((rc + 1 < C_OUT) ? b2[rc + 1] : 0.0f);
                o.z = acc[i][2] + ((rc + 2 < C_OUT) ? b2[rc + 2] : 0.0f);
                o.w = acc[i][3] + ((rc + 3 < C_OUT) ? b2[rc + 3] : 0.0f);
                *(float4*)(r + (size_t)m * ZP + rc) = o;
            }
        }
    }
}

// ---------------------------------------------------------------------------
// agg2: out = log_softmax_segments( mean-agg(z) + r ). z rows 32 B bf16.
// ---------------------------------------------------------------------------
__global__ __launch_bounds__(256) void agg2_kernel(
    const unsigned short* __restrict__ z, const float* __restrict__ r,
    const int* __restrict__ eidx, const int* __restrict__ rowptr,
    const int* __restrict__ cnt, const float* __restrict__ invdeg,
    const int* __restrict__ sf_ptr, float* __restrict__ out)
{
    __shared__ float sm[64][ZP + 1];

    const int lane4 = threadIdx.x & 3;
    const int slot  = threadIdx.x >> 2;
    const int n     = blockIdx.x * 64 + slot;
    const int j4    = lane4 * 4;

    if (n < NN) {
        const int start = rowptr[n];
        const int len   = cnt[n];
        float4 a0 = make_float4(0.f, 0.f, 0.f, 0.f);
        float4 a1 = a0, a2 = a0, a3 = a0;
        int i = 0;
        for (; i + 4 <= len; i += 4) {
            const int s0 = eidx[start + i + 0];
            const int s1 = eidx[start + i + 1];
            const int s2 = eidx[start + i + 2];
            const int s3 = eidx[start + i + 3];
            const uint2 u0 = *(const uint2*)(z + (size_t)s0 * ZP + j4);
            const uint2 u1 = *(const uint2*)(z + (size_t)s1 * ZP + j4);
            const uint2 u2 = *(const uint2*)(z + (size_t)s2 * ZP + j4);
            const uint2 u3 = *(const uint2*)(z + (size_t)s3 * ZP + j4);
            float f0, f1, f2, f3;
            unpack2(u0.x, f0, f1); unpack2(u0.y, f2, f3);
            a0.x += f0; a0.y += f1; a0.z += f2; a0.w += f3;
            unpack2(u1.x, f0, f1); unpack2(u1.y, f2, f3);
            a1.x += f0; a1.y += f1; a1.z += f2; a1.w += f3;
            unpack2(u2.x, f0, f1); unpack2(u2.y, f2, f3);
            a2.x += f0; a2.y += f1; a2.z += f2; a2.w += f3;
            unpack2(u3.x, f0, f1); unpack2(u3.y, f2, f3);
            a3.x += f0; a3.y += f1; a3.z += f2; a3.w += f3;
        }
        for (; i < len; ++i) {
            const int s = eidx[start + i];
            const uint2 u = *(const uint2*)(z + (size_t)s * ZP + j4);
            float f0, f1, f2, f3;
            unpack2(u.x, f0, f1); unpack2(u.y, f2, f3);
            a0.x += f0; a0.y += f1; a0.z += f2; a0.w += f3;
        }
        const float inv = invdeg[n];
        const float4 rv = *(const float4*)(r + (size_t)n * ZP + j4);
        sm[slot][j4 + 0] = (a0.x + a1.x + a2.x + a3.x) * inv + rv.x;
        sm[slot][j4 + 1] = (a0.y + a1.y + a2.y + a3.y) * inv + rv.y;
        sm[slot][j4 + 2] = (a0.z + a1.z + a2.z + a3.z) * inv + rv.z;
        sm[slot][j4 + 3] = (a0.w + a1.w + a2.w + a3.w) * inv + rv.w;
    }
    __syncthreads();

    if (threadIdx.x < 64) {
        const int n2 = blockIdx.x * 64 + threadIdx.x;
        if (n2 < NN) {
            const int sf = *sf_ptr;
            const float* row = sm[threadIdx.x];
            float m = -1e30f;
            for (int c = 0; c < sf; ++c) m = fmaxf(m, row[c]);
            float s = 0.0f;
            for (int c = 0; c < sf; ++c) s += expf(row[c] - m);
            float ls = m + logf(s);
            for (int c = 0; c < sf; ++c)
                out[(long long)n2 * sf + c] = row[c] - ls;
            m = -1e30f;
            for (int c = sf; c < C_OUT; ++c) m = fmaxf(m, row[c]);
            s = 0.0f;
            for (int c = sf; c < C_OUT; ++c) s += expf(row[c] - m);
            ls = m + logf(s);
            const int pt = C_OUT - sf;
            for (int c = sf; c < C_OUT; ++c)
                out[(long long)NN * sf + (long long)n2 * pt + (c - sf)] = row[c] - ls;
        }
    }
}

// ---------------------------------------------------------------------------
extern "C" void kernel_launch(void* const* d_in, const int* in_sizes, int n_in,
                              void* d_out, int out_size, void* d_ws, size_t ws_size,
                              hipStream_t stream)
{
    const float* x   = (const float*)d_in[0];
    const int*   ei  = (const int*)d_in[1];
    const int*   sfp = (const int*)d_in[2];
    const float* W1l = (const float*)d_in[3];
    const float* W1r = (const float*)d_in[4];
    const float* b1  = (const float*)d_in[5];
    const float* W2l = (const float*)d_in[6];
    const float* W2r = (const float*)d_in[7];
    const float* b2  = (const float*)d_in[8];
    float*       out = (float*)d_out;

    const int E  = in_sizes[1] / 2;
    const int E4 = (E + 3) & ~3;
    const int* src = ei;
    const int* dst = ei + E;

    // ws layout (words), aliasing: z over pq (pq dead after agg1).
    int*   cnt      = (int*)d_ws;                          // NN
    int*   rowptr   = cnt + NN;                            // NN
    int*   cursor   = rowptr + NN;                         // NN
    float* invdeg   = (float*)(cursor + NN);               // NN
    int*   blocksum = (int*)(invdeg + NN);                 // 128
    int*   eidx     = blocksum + 128;                      // E4
    unsigned short* hb = (unsigned short*)(eidx + E4);     // NN*F bf16 (25.6 MB)
    unsigned short* pq = hb + (size_t)NN * F;              // NN*256 bf16 (51.2 MB)
    unsigned short* z  = pq;                               // alias
    float*          r  = (float*)(pq + (size_t)NN * ZP);   // after z

    hipMemsetAsync(cnt, 0, (size_t)NN * sizeof(int), stream);

    const int pblocks = ((E + 1023) / 1024) * NPART;       // partitioned grid
    const int nblocks = (NN + 255) / 256;

    // CSR build (dst-range partitioned, XCD-swizzled)
    hist_kernel      <<<pblocks, 256, 0, stream>>>(dst, cnt, E);
    scan_local_kernel<<<NBLK,    256, 0, stream>>>(cnt, rowptr, blocksum);
    scan_block_kernel<<<1,       128, 0, stream>>>(blocksum);
    finalize_kernel  <<<nblocks, 256, 0, stream>>>(cnt, rowptr, cursor, invdeg, blocksum);
    fill_kernel      <<<pblocks, 256, 0, stream>>>(src, dst, cursor, eidx, E);

    // layer 1 (commuted): pq = [x@W1l | x@W1r+b1], then gather-mean + relu
    dim3 g1((NN + 127) / 128, 2);
    pre1_kernel<<<g1, 256, 0, stream>>>(x, W1l, W1r, b1, pq);
    agg1_kernel<<<(NN + 15) / 16, 256, 0, stream>>>(pq, eidx, rowptr, cnt, invdeg, hb);

    // layer 2 (commuted): [z|r] = hb@[W2l|W2r], then gather-mean + softmax
    pre2_kernel<<<(NN + 127) / 128, 256, 0, stream>>>(hb, W2l, W2r, b2, z, r);
    agg2_kernel<<<(NN + 63) / 64, 256, 0, stream>>>(z, r, eidx, rowptr, cnt, invdeg,
                                                    sfp, out);
}

// Round 6
// 392.347 us; speedup vs baseline: 15.2472x; 1.1630x over previous
//
#include <hip/hip_runtime.h>
#include <hip/hip_bf16.h>

#define NN 100000
#define F 128
#define C_OUT 14
#define ZP 16
#define SCAN_CHUNK 1024
#define NBLK ((NN + SCAN_CHUNK - 1) / SCAN_CHUNK)   // 98 blocks
#define NPART 8
#define PART_SZ ((NN + NPART - 1) / NPART)          // 12500

typedef __attribute__((ext_vector_type(8))) short v8s;   // 8 bf16 (4 VGPRs)
typedef __attribute__((ext_vector_type(4))) float v4f;   // 4 fp32 acc

// ---------------- bf16 helpers (manual, zero API risk) ----------------------
static __device__ __forceinline__ unsigned short f2bf(float f) {
    unsigned int u = __float_as_uint(f);
    unsigned int r = (u + 0x7fffu + ((u >> 16) & 1u)) >> 16;   // RTN-even
    return (unsigned short)r;
}
static __device__ __forceinline__ unsigned int pack2(float a, float b) {
    return (unsigned int)f2bf(a) | ((unsigned int)f2bf(b) << 16);
}
static __device__ __forceinline__ void unpack2(unsigned int u, float& lo, float& hi) {
    lo = __uint_as_float(u << 16);
    hi = __uint_as_float(u & 0xffff0000u);
}

// ---------------------------- CSR build ------------------------------------
__global__ __launch_bounds__(256) void hist_kernel(
    const int* __restrict__ dst, int* __restrict__ cnt, int E)
{
    const int part = blockIdx.x & (NPART - 1);
    const int lo   = part * PART_SZ;
    const int hi   = min(lo + PART_SZ, NN);
    const int e0   = ((blockIdx.x >> 3) * 256 + threadIdx.x) * 4;
    if (e0 + 3 < E) {
        const int4 d = *(const int4*)(dst + e0);
        if (d.x >= lo && d.x < hi) atomicAdd(&cnt[d.x], 1);
        if (d.y >= lo && d.y < hi) atomicAdd(&cnt[d.y], 1);
        if (d.z >= lo && d.z < hi) atomicAdd(&cnt[d.z], 1);
        if (d.w >= lo && d.w < hi) atomicAdd(&cnt[d.w], 1);
    } else {
        for (int e = e0; e < E; ++e) {
            const int d = dst[e];
            if (d >= lo && d < hi) atomicAdd(&cnt[d], 1);
        }
    }
}

__global__ __launch_bounds__(256) void scan_local_kernel(
    const int* __restrict__ cnt, int* __restrict__ rowptr,
    int* __restrict__ blocksum)
{
    __shared__ int sm[256];
    const int tid  = threadIdx.x;
    const int base = blockIdx.x * SCAN_CHUNK + tid * 4;
    int v0 = (base + 0 < NN) ? cnt[base + 0] : 0;
    int v1 = (base + 1 < NN) ? cnt[base + 1] : 0;
    int v2 = (base + 2 < NN) ? cnt[base + 2] : 0;
    int v3 = (base + 3 < NN) ? cnt[base + 3] : 0;
    const int t = v0 + v1 + v2 + v3;
    sm[tid] = t;
    __syncthreads();
    int acc = t;
    for (int off = 1; off < 256; off <<= 1) {
        int other = (tid >= off) ? sm[tid - off] : 0;
        __syncthreads();
        acc += other;
        sm[tid] = acc;
        __syncthreads();
    }
    const int excl = acc - t;
    if (base + 0 < NN) rowptr[base + 0] = excl;
    if (base + 1 < NN) rowptr[base + 1] = excl + v0;
    if (base + 2 < NN) rowptr[base + 2] = excl + v0 + v1;
    if (base + 3 < NN) rowptr[base + 3] = excl + v0 + v1 + v2;
    if (tid == 255) blocksum[blockIdx.x] = acc;
}

__global__ __launch_bounds__(128) void scan_block_kernel(int* __restrict__ blocksum)
{
    __shared__ int sm[128];
    const int tid = threadIdx.x;
    const int v = (tid < NBLK) ? blocksum[tid] : 0;
    sm[tid] = v;
    __syncthreads();
    int acc = v;
    for (int off = 1; off < 128; off <<= 1) {
        int other = (tid >= off) ? sm[tid - off] : 0;
        __syncthreads();
        acc += other;
        sm[tid] = acc;
        __syncthreads();
    }
    if (tid < NBLK) blocksum[tid] = acc - v;
}

__global__ __launch_bounds__(256) void finalize_kernel(
    const int* __restrict__ cnt, int* __restrict__ rowptr,
    int* __restrict__ cursor, float* __restrict__ invdeg,
    const int* __restrict__ blocksum)
{
    int i = blockIdx.x * 256 + threadIdx.x;
    if (i >= NN) return;
    int r = rowptr[i] + blocksum[i / SCAN_CHUNK];
    rowptr[i] = r;
    cursor[i] = r;
    invdeg[i] = 1.0f / (float)max(cnt[i], 1);
}

__global__ __launch_bounds__(256) void fill_kernel(
    const int* __restrict__ src, const int* __restrict__ dst,
    int* __restrict__ cursor, int* __restrict__ eidx, int E)
{
    const int part = blockIdx.x & (NPART - 1);
    const int lo   = part * PART_SZ;
    const int hi   = min(lo + PART_SZ, NN);
    const int e0   = ((blockIdx.x >> 3) * 256 + threadIdx.x) * 4;
    if (e0 + 3 < E) {
        const int4 d = *(const int4*)(dst + e0);
        if (d.x >= lo && d.x < hi) { int p = atomicAdd(&cursor[d.x], 1); eidx[p] = src[e0 + 0]; }
        if (d.y >= lo && d.y < hi) { int p = atomicAdd(&cursor[d.y], 1); eidx[p] = src[e0 + 1]; }
        if (d.z >= lo && d.z < hi) { int p = atomicAdd(&cursor[d.z], 1); eidx[p] = src[e0 + 2]; }
        if (d.w >= lo && d.w < hi) { int p = atomicAdd(&cursor[d.w], 1); eidx[p] = src[e0 + 3]; }
    } else {
        for (int e = e0; e < E; ++e) {
            const int d = dst[e];
            if (d >= lo && d < hi) { int p = atomicAdd(&cursor[d], 1); eidx[p] = src[e]; }
        }
    }
}

// ---------------------------------------------------------------------------
// wprep: Wb[n][k] = bf16 of [W1l | W1r] transposed; n in [0,256), k in [0,128).
// One-time 32768-element transpose so pre1's B-fragments are contiguous.
// ---------------------------------------------------------------------------
__global__ __launch_bounds__(256) void wprep_kernel(
    const float* __restrict__ W1l, const float* __restrict__ W1r,
    unsigned short* __restrict__ Wb)
{
    const int idx = blockIdx.x * 256 + threadIdx.x;
    if (idx >= 2 * 128 * 128) return;
    const int c   = idx >> 14;           // 0 -> W1l, 1 -> W1r
    const int rem = idx & 16383;
    const int n   = rem >> 7;
    const int k   = rem & 127;
    const float* W = c ? W1r : W1l;
    Wb[idx] = f2bf(W[k * 128 + n]);
}

// ---------------------------------------------------------------------------
// pre1 (MFMA): pq = [ x@W1l | x@W1r + b1 ]  (bf16, [NN][256]).
// Block = 128 m x 256 n; 4 waves, wave w owns n in [w*64, w*64+64):
// 8 m-tiles x 4 n-tiles of 16x16x32 bf16 MFMA (32 v4f accumulators).
// K=128 staged in two 64-wide LDS phases: A_s[128][72] + W_s[256][72] = 54 KB.
// Fragment layouts (HW-verified, guide m89/m120): A[m=lane&15][k=quad*8+j],
// B[k=quad*8+j][n=lane&15], D[row=quad*4+r][col=lane&15].
// Epilogue: D -> LDS (bf16) -> coalesced uint4 stores, two 128-col passes.
// ---------------------------------------------------------------------------
#define KS 72   // padded k-stride (shorts): 144 B, 16B-aligned, breaks pow2 banks
__global__ __launch_bounds__(256, 2) void pre1_kernel(
    const float* __restrict__ x, const unsigned short* __restrict__ Wb,
    const float* __restrict__ b1, unsigned short* __restrict__ pq)
{
    __shared__ unsigned short lds[128 * KS + 256 * KS];   // 55296 B
    unsigned short* A_s = lds;              // [128][KS]
    unsigned short* W_s = lds + 128 * KS;   // [256][KS]

    const int t    = threadIdx.x;
    const int m0   = blockIdx.x * 128;
    const int lane = t & 63;
    const int wave = t >> 6;
    const int lr   = lane & 15;
    const int quad = lane >> 4;
    const int nw0  = wave * 64;

    v4f acc[8][4];
    #pragma unroll
    for (int mt = 0; mt < 8; ++mt)
        #pragma unroll
        for (int nt = 0; nt < 4; ++nt)
            acc[mt][nt] = (v4f){0.f, 0.f, 0.f, 0.f};

    #pragma unroll
    for (int ph = 0; ph < 2; ++ph) {
        const int kh = ph * 64;
        if (ph) __syncthreads();   // protect LDS from previous phase's readers

        // stage A half: thread -> row mi = t&127, 32-k quarter ko
        {
            const int mi = t & 127;
            const int ko = (t >> 7) * 32;
            const int m  = m0 + mi;
            unsigned short* dp = &A_s[mi * KS + ko];
            if (m < NN) {
                const float4* sp = (const float4*)(x + (size_t)m * F + kh + ko);
                #pragma unroll
                for (int j = 0; j < 8; j += 2) {
                    const float4 f0 = sp[j], f1 = sp[j + 1];
                    uint4 o;
                    o.x = pack2(f0.x, f0.y); o.y = pack2(f0.z, f0.w);
                    o.z = pack2(f1.x, f1.y); o.w = pack2(f1.z, f1.w);
                    *(uint4*)(dp + j * 4) = o;
                }
            } else {
                #pragma unroll
                for (int j = 0; j < 4; ++j)
                    *(uint4*)(dp + j * 8) = make_uint4(0u, 0u, 0u, 0u);
            }
        }
        // stage W half: thread -> row n = t (256 rows), 64 k
        {
            const unsigned short* sp = Wb + (size_t)t * 128 + kh;
            unsigned short* dp = &W_s[t * KS];
            #pragma unroll
            for (int j = 0; j < 8; ++j)
                *(uint4*)(dp + j * 8) = *(const uint4*)(sp + j * 8);
        }
        __syncthreads();

        #pragma unroll
        for (int ks = 0; ks < 2; ++ks) {
            const int k0 = ks * 32 + quad * 8;
            const v8s b0 = *(const v8s*)&W_s[(nw0 +  0 + lr) * KS + k0];
            const v8s b1v= *(const v8s*)&W_s[(nw0 + 16 + lr) * KS + k0];
            const v8s b2 = *(const v8s*)&W_s[(nw0 + 32 + lr) * KS + k0];
            const v8s b3 = *(const v8s*)&W_s[(nw0 + 48 + lr) * KS + k0];
            #pragma unroll
            for (int mt = 0; mt < 8; ++mt) {
                const v8s a = *(const v8s*)&A_s[(mt * 16 + lr) * KS + k0];
                acc[mt][0] = __builtin_amdgcn_mfma_f32_16x16x32_bf16(a, b0,  acc[mt][0], 0, 0, 0);
                acc[mt][1] = __builtin_amdgcn_mfma_f32_16x16x32_bf16(a, b1v, acc[mt][1], 0, 0, 0);
                acc[mt][2] = __builtin_amdgcn_mfma_f32_16x16x32_bf16(a, b2,  acc[mt][2], 0, 0, 0);
                acc[mt][3] = __builtin_amdgcn_mfma_f32_16x16x32_bf16(a, b3,  acc[mt][3], 0, 0, 0);
            }
        }
        __syncthreads();
    }

    // bias (cols >= 128 are the W1r chunk)
    float bias[4];
    #pragma unroll
    for (int nt = 0; nt < 4; ++nt) {
        const int n = nw0 + nt * 16 + lr;
        bias[nt] = (n >= 128) ? b1[n - 128] : 0.0f;
    }

    // epilogue: two 128-col passes through LDS ([128][136] bf16)
    unsigned short* C_s = lds;
    #pragma unroll
    for (int p = 0; p < 2; ++p) {
        if ((nw0 >> 7) == p) {
            #pragma unroll
            for (int mt = 0; mt < 8; ++mt)
                #pragma unroll
                for (int nt = 0; nt < 4; ++nt) {
                    const int n = (nw0 & 127) + nt * 16 + lr;
                    #pragma unroll
                    for (int r = 0; r < 4; ++r) {
                        const int m = mt * 16 + quad * 4 + r;
                        C_s[m * 136 + n] = f2bf(acc[mt][nt][r] + bias[nt]);
                    }
                }
        }
        __syncthreads();
        {
            const int mi = t & 127;
            const int nh = (t >> 7) * 64;
            const int m  = m0 + mi;
            if (m < NN) {
                unsigned short* dp = pq + (size_t)m * 256 + p * 128 + nh;
                const unsigned short* sp = &C_s[mi * 136 + nh];
                #pragma unroll
                for (int j = 0; j < 8; ++j)
                    *(uint4*)(dp + j * 8) = *(const uint4*)(sp + j * 8);
            }
        }
        __syncthreads();
    }
}

// ---------------------------------------------------------------------------
// agg1: hb[n] = bf16( relu( mean_j p[j] + q[n] ) ). 16 lanes per node,
// uint4 (16 B) per lane, gather unrolled x4 for MLP.
// ---------------------------------------------------------------------------
__global__ __launch_bounds__(256) void agg1_kernel(
    const unsigned short* __restrict__ pq, const int* __restrict__ eidx,
    const int* __restrict__ rowptr, const int* __restrict__ cnt,
    const float* __restrict__ invdeg, unsigned short* __restrict__ hb)
{
    const int lane = threadIdx.x & 15;
    const int sub  = threadIdx.x >> 4;
    const int n    = blockIdx.x * 16 + sub;
    if (n >= NN) return;
    const int col = lane * 8;

    const int start = rowptr[n];
    const int len   = cnt[n];
    float a0[8] = {0,0,0,0,0,0,0,0};
    float a1[8] = {0,0,0,0,0,0,0,0};
    float a2[8] = {0,0,0,0,0,0,0,0};
    float a3[8] = {0,0,0,0,0,0,0,0};
    int i = 0;
    for (; i + 4 <= len; i += 4) {
        const int s0 = eidx[start + i + 0];
        const int s1 = eidx[start + i + 1];
        const int s2 = eidx[start + i + 2];
        const int s3 = eidx[start + i + 3];
        const uint4 u0 = *(const uint4*)(pq + (size_t)s0 * 256 + col);
        const uint4 u1 = *(const uint4*)(pq + (size_t)s1 * 256 + col);
        const uint4 u2 = *(const uint4*)(pq + (size_t)s2 * 256 + col);
        const uint4 u3 = *(const uint4*)(pq + (size_t)s3 * 256 + col);
        float f0, f1;
        unpack2(u0.x, f0, f1); a0[0] += f0; a0[1] += f1;
        unpack2(u0.y, f0, f1); a0[2] += f0; a0[3] += f1;
        unpack2(u0.z, f0, f1); a0[4] += f0; a0[5] += f1;
        unpack2(u0.w, f0, f1); a0[6] += f0; a0[7] += f1;
        unpack2(u1.x, f0, f1); a1[0] += f0; a1[1] += f1;
        unpack2(u1.y, f0, f1); a1[2] += f0; a1[3] += f1;
        unpack2(u1.z, f0, f1); a1[4] += f0; a1[5] += f1;
        unpack2(u1.w, f0, f1); a1[6] += f0; a1[7] += f1;
        unpack2(u2.x, f0, f1); a2[0] += f0; a2[1] += f1;
        unpack2(u2.y, f0, f1); a2[2] += f0; a2[3] += f1;
        unpack2(u2.z, f0, f1); a2[4] += f0; a2[5] += f1;
        unpack2(u2.w, f0, f1); a2[6] += f0; a2[7] += f1;
        unpack2(u3.x, f0, f1); a3[0] += f0; a3[1] += f1;
        unpack2(u3.y, f0, f1); a3[2] += f0; a3[3] += f1;
        unpack2(u3.z, f0, f1); a3[4] += f0; a3[5] += f1;
        unpack2(u3.w, f0, f1); a3[6] += f0; a3[7] += f1;
    }
    for (; i < len; ++i) {
        const int s = eidx[start + i];
        const uint4 u = *(const uint4*)(pq + (size_t)s * 256 + col);
        float f0, f1;
        unpack2(u.x, f0, f1); a0[0] += f0; a0[1] += f1;
        unpack2(u.y, f0, f1); a0[2] += f0; a0[3] += f1;
        unpack2(u.z, f0, f1); a0[4] += f0; a0[5] += f1;
        unpack2(u.w, f0, f1); a0[6] += f0; a0[7] += f1;
    }
    const float inv = invdeg[n];
    const uint4 uq = *(const uint4*)(pq + (size_t)n * 256 + 128 + col);
    float q[8];
    unpack2(uq.x, q[0], q[1]); unpack2(uq.y, q[2], q[3]);
    unpack2(uq.z, q[4], q[5]); unpack2(uq.w, q[6], q[7]);
    float hv[8];
    #pragma unroll
    for (int j = 0; j < 8; ++j)
        hv[j] = fmaxf((a0[j] + a1[j] + a2[j] + a3[j]) * inv + q[j], 0.0f);
    uint4 o;
    o.x = pack2(hv[0], hv[1]);
    o.y = pack2(hv[2], hv[3]);
    o.z = pack2(hv[4], hv[5]);
    o.w = pack2(hv[6], hv[7]);
    *(uint4*)(hb + (size_t)n * F + col) = o;
}

// ---------------------------------------------------------------------------
// pre2: [z | r] = hb @ [W2l | W2r]; z bf16 [NN][16], r fp32 [NN][16] + bias.
// ---------------------------------------------------------------------------
__global__ __launch_bounds__(256, 2) void pre2_kernel(
    const unsigned short* __restrict__ hb,
    const float* __restrict__ W2l, const float* __restrict__ W2r,
    const float* __restrict__ b2,
    unsigned short* __restrict__ z, float* __restrict__ r)
{
    __shared__ unsigned short A_s[128 * 128];   // [k][m] 32 KB
    __shared__ unsigned short W_s[128 * 32];    // [k][c] 8 KB

    const int t  = threadIdx.x;
    const int m0 = blockIdx.x * 128;

    {
        const int mloc = t & 127;
        const int kc   = (t >> 7) * 64;
        const int m    = m0 + mloc;
        #pragma unroll
        for (int j = 0; j < 8; ++j) {
            const int k = kc + j * 8;
            uint4 u = make_uint4(0u, 0u, 0u, 0u);
            if (m < NN) u = *(const uint4*)(hb + (size_t)m * F + k);
            A_s[(k + 0) * 128 + mloc] = (unsigned short)(u.x & 0xffffu);
            A_s[(k + 1) * 128 + mloc] = (unsigned short)(u.x >> 16);
            A_s[(k + 2) * 128 + mloc] = (unsigned short)(u.y & 0xffffu);
            A_s[(k + 3) * 128 + mloc] = (unsigned short)(u.y >> 16);
            A_s[(k + 4) * 128 + mloc] = (unsigned short)(u.z & 0xffffu);
            A_s[(k + 5) * 128 + mloc] = (unsigned short)(u.z >> 16);
            A_s[(k + 6) * 128 + mloc] = (unsigned short)(u.w & 0xffffu);
            A_s[(k + 7) * 128 + mloc] = (unsigned short)(u.w >> 16);
        }
    }
    #pragma unroll
    for (int rr = 0; rr < 16; ++rr) {
        const int idx = rr * 256 + t;
        const int k = idx >> 5;
        const int c = idx & 31;
        float wv = 0.0f;
        if (c < 16) { if (c < C_OUT) wv = W2l[k * C_OUT + c]; }
        else        { if (c - 16 < C_OUT) wv = W2r[k * C_OUT + (c - 16)]; }
        W_s[k * 32 + c] = f2bf(wv);
    }
    __syncthreads();

    const int mq = t & 31;
    const int nq = t >> 5;
    float acc[4][4];
    #pragma unroll
    for (int i = 0; i < 4; ++i)
        #pragma unroll
        for (int j = 0; j < 4; ++j) acc[i][j] = 0.0f;

    #pragma unroll 4
    for (int k = 0; k < 128; ++k) {
        const uint2 ua = *(const uint2*)&A_s[k * 128 + mq * 4];
        const uint2 uw = *(const uint2*)&W_s[k * 32 + nq * 4];
        float a[4], w[4];
        unpack2(ua.x, a[0], a[1]); unpack2(ua.y, a[2], a[3]);
        unpack2(uw.x, w[0], w[1]); unpack2(uw.y, w[2], w[3]);
        #pragma unroll
        for (int i = 0; i < 4; ++i)
            #pragma unroll
            for (int j = 0; j < 4; ++j)
                acc[i][j] += a[i] * w[j];
    }

    const int c0 = nq * 4;
    #pragma unroll
    for (int i = 0; i < 4; ++i) {
        const int m = m0 + mq * 4 + i;
        if (m < NN) {
            if (nq < 4) {
                uint2 o;
                o.x = pack2(acc[i][0], acc[i][1]);
                o.y = pack2(acc[i][2], acc[i][3]);
                *(uint2*)(z + (size_t)m * ZP + c0) = o;
            } else {
                const int rc = c0 - 16;
                float4 o;
                o.x = acc[i][0] + ((rc + 0 < C_OUT) ? b2[rc + 0] : 0.0f);
                o.y = acc[i][1] + ((rc + 1 < C_OUT) ? b2[rc + 1] : 0.0f);
                o.z = acc[i][2] + ((rc + 2 < C_OUT) ? b2[rc + 2] : 0.0f);
                o.w = acc[i][3] + ((rc + 3 < C_OUT) ? b2[rc + 3] : 0.0f);
                *(float4*)(r + (size_t)m * ZP + rc) = o;
            }
        }
    }
}

// ---------------------------------------------------------------------------
// agg2: out = log_softmax_segments( mean-agg(z) + r ). z rows 32 B bf16.
// ---------------------------------------------------------------------------
__global__ __launch_bounds__(256) void agg2_kernel(
    const unsigned short* __restrict__ z, const float* __restrict__ r,
    const int* __restrict__ eidx, const int* __restrict__ rowptr,
    const int* __restrict__ cnt, const float* __restrict__ invdeg,
    const int* __restrict__ sf_ptr, float* __restrict__ out)
{
    __shared__ float sm[64][ZP + 1];

    const int lane4 = threadIdx.x & 3;
    const int slot  = threadIdx.x >> 2;
    const int n     = blockIdx.x * 64 + slot;
    const int j4    = lane4 * 4;

    if (n < NN) {
        const int start = rowptr[n];
        const int len   = cnt[n];
        float4 a0 = make_float4(0.f, 0.f, 0.f, 0.f);
        float4 a1 = a0, a2 = a0, a3 = a0;
        int i = 0;
        for (; i + 4 <= len; i += 4) {
            const int s0 = eidx[start + i + 0];
            const int s1 = eidx[start + i + 1];
            const int s2 = eidx[start + i + 2];
            const int s3 = eidx[start + i + 3];
            const uint2 u0 = *(const uint2*)(z + (size_t)s0 * ZP + j4);
            const uint2 u1 = *(const uint2*)(z + (size_t)s1 * ZP + j4);
            const uint2 u2 = *(const uint2*)(z + (size_t)s2 * ZP + j4);
            const uint2 u3 = *(const uint2*)(z + (size_t)s3 * ZP + j4);
            float f0, f1, f2, f3;
            unpack2(u0.x, f0, f1); unpack2(u0.y, f2, f3);
            a0.x += f0; a0.y += f1; a0.z += f2; a0.w += f3;
            unpack2(u1.x, f0, f1); unpack2(u1.y, f2, f3);
            a1.x += f0; a1.y += f1; a1.z += f2; a1.w += f3;
            unpack2(u2.x, f0, f1); unpack2(u2.y, f2, f3);
            a2.x += f0; a2.y += f1; a2.z += f2; a2.w += f3;
            unpack2(u3.x, f0, f1); unpack2(u3.y, f2, f3);
            a3.x += f0; a3.y += f1; a3.z += f2; a3.w += f3;
        }
        for (; i < len; ++i) {
            const int s = eidx[start + i];
            const uint2 u = *(const uint2*)(z + (size_t)s * ZP + j4);
            float f0, f1, f2, f3;
            unpack2(u.x, f0, f1); unpack2(u.y, f2, f3);
            a0.x += f0; a0.y += f1; a0.z += f2; a0.w += f3;
        }
        const float inv = invdeg[n];
        const float4 rv = *(const float4*)(r + (size_t)n * ZP + j4);
        sm[slot][j4 + 0] = (a0.x + a1.x + a2.x + a3.x) * inv + rv.x;
        sm[slot][j4 + 1] = (a0.y + a1.y + a2.y + a3.y) * inv + rv.y;
        sm[slot][j4 + 2] = (a0.z + a1.z + a2.z + a3.z) * inv + rv.z;
        sm[slot][j4 + 3] = (a0.w + a1.w + a2.w + a3.w) * inv + rv.w;
    }
    __syncthreads();

    if (threadIdx.x < 64) {
        const int n2 = blockIdx.x * 64 + threadIdx.x;
        if (n2 < NN) {
            const int sf = *sf_ptr;
            const float* row = sm[threadIdx.x];
            float m = -1e30f;
            for (int c = 0; c < sf; ++c) m = fmaxf(m, row[c]);
            float s = 0.0f;
            for (int c = 0; c < sf; ++c) s += expf(row[c] - m);
            float ls = m + logf(s);
            for (int c = 0; c < sf; ++c)
                out[(long long)n2 * sf + c] = row[c] - ls;
            m = -1e30f;
            for (int c = sf; c < C_OUT; ++c) m = fmaxf(m, row[c]);
            s = 0.0f;
            for (int c = sf; c < C_OUT; ++c) s += expf(row[c] - m);
            ls = m + logf(s);
            const int pt = C_OUT - sf;
            for (int c = sf; c < C_OUT; ++c)
                out[(long long)NN * sf + (long long)n2 * pt + (c - sf)] = row[c] - ls;
        }
    }
}

// ---------------------------------------------------------------------------
extern "C" void kernel_launch(void* const* d_in, const int* in_sizes, int n_in,
                              void* d_out, int out_size, void* d_ws, size_t ws_size,
                              hipStream_t stream)
{
    const float* x   = (const float*)d_in[0];
    const int*   ei  = (const int*)d_in[1];
    const int*   sfp = (const int*)d_in[2];
    const float* W1l = (const float*)d_in[3];
    const float* W1r = (const float*)d_in[4];
    const float* b1  = (const float*)d_in[5];
    const float* W2l = (const float*)d_in[6];
    const float* W2r = (const float*)d_in[7];
    const float* b2  = (const float*)d_in[8];
    float*       out = (float*)d_out;

    const int E  = in_sizes[1] / 2;
    const int E4 = (E + 3) & ~3;
    const int* src = ei;
    const int* dst = ei + E;

    // ws layout (words), aliasing: z over pq (pq dead after agg1).
    int*   cnt      = (int*)d_ws;                          // NN
    int*   rowptr   = cnt + NN;                            // NN
    int*   cursor   = rowptr + NN;                         // NN
    float* invdeg   = (float*)(cursor + NN);               // NN
    int*   blocksum = (int*)(invdeg + NN);                 // 128
    int*   eidx     = blocksum + 128;                      // E4
    unsigned short* Wb = (unsigned short*)(eidx + E4);     // 2*128*128 bf16 (64 KB)
    unsigned short* hb = Wb + 2 * 128 * 128;               // NN*F bf16 (25.6 MB)
    unsigned short* pq = hb + (size_t)NN * F;              // NN*256 bf16 (51.2 MB)
    unsigned short* z  = pq;                               // alias
    float*          r  = (float*)(pq + (size_t)NN * ZP);   // after z

    hipMemsetAsync(cnt, 0, (size_t)NN * sizeof(int), stream);

    const int pblocks = ((E + 1023) / 1024) * NPART;
    const int nblocks = (NN + 255) / 256;

    // CSR build (dst-range partitioned, XCD-swizzled)
    hist_kernel      <<<pblocks, 256, 0, stream>>>(dst, cnt, E);
    scan_local_kernel<<<NBLK,    256, 0, stream>>>(cnt, rowptr, blocksum);
    scan_block_kernel<<<1,       128, 0, stream>>>(blocksum);
    finalize_kernel  <<<nblocks, 256, 0, stream>>>(cnt, rowptr, cursor, invdeg, blocksum);
    fill_kernel      <<<pblocks, 256, 0, stream>>>(src, dst, cursor, eidx, E);

    // weight prep for MFMA pre1 (no deps on CSR; tiny)
    wprep_kernel<<<128, 256, 0, stream>>>(W1l, W1r, Wb);

    // layer 1 (commuted): pq = [x@W1l | x@W1r+b1] via MFMA, then gather-mean
    pre1_kernel<<<(NN + 127) / 128, 256, 0, stream>>>(x, Wb, b1, pq);
    agg1_kernel<<<(NN + 15) / 16, 256, 0, stream>>>(pq, eidx, rowptr, cnt, invdeg, hb);

    // layer 2 (commuted): [z|r] = hb@[W2l|W2r], then gather-mean + softmax
    pre2_kernel<<<(NN + 127) / 128, 256, 0, stream>>>(hb, W2l, W2r, b2, z, r);
    agg2_kernel<<<(NN + 63) / 64, 256, 0, stream>>>(z, r, eidx, rowptr, cnt, invdeg,
                                                    sfp, out);
}